// Round 1
// baseline (4163.319 us; speedup 1.0000x reference)
//
#include <hip/hip_runtime.h>
#include <hip/hip_bf16.h>
#include <cmath>

#define DIM  960
#define NH   15
#define NKV  5
#define HD   64
#define GQ   3          // NH / NKV
#define TSEQ 2048
#define BATCH 4
#define NQ   (NH * HD)        // 960
#define NKVD (NKV * HD)       // 320
#define NTOT (NQ + 2 * NKVD)  // 1600

// ---------------------------------------------------------------------------
// Tiled fp32 GEMM: C = A(MxK) @ B(KxN). 64x64 tile, BK=16, 256 threads,
// 4x4 microtile per thread. EPI==1: fused QKV projection + RoPE epilogue
// (B0=wq, B1=wk, B2=wv; C0=q, C1=k, C2=v). EPI==0: plain store to C0.
// ---------------------------------------------------------------------------
template<int EPI>
__global__ __launch_bounds__(256)
void gemm64(const float* __restrict__ A,
            const float* __restrict__ B0,
            const float* __restrict__ B1,
            const float* __restrict__ B2,
            float* __restrict__ C0,
            float* __restrict__ C1,
            float* __restrict__ C2,
            const float* __restrict__ fcos,
            const float* __restrict__ fsin,
            int M, int N, int K)
{
    __shared__ float As[16][68];   // A^T tile, padded (stride 68 keeps 16B align)
    __shared__ float Bs[16][68];

    const int row0 = blockIdx.y * 64;
    const int col0 = blockIdx.x * 64;
    const int tid  = threadIdx.x;
    const int ty   = tid >> 4;     // 0..15
    const int tx   = tid & 15;     // 0..15

    float acc[4][4] = {};

    for (int k0 = 0; k0 < K; k0 += 16) {
        // ---- A tile: 64 rows x 16 k (each thread one float4 along k) ----
        {
            const int i  = tid * 4;
            const int ar = i >> 4;       // 0..63
            const int ak = i & 15;       // 0,4,8,12
            float4 v = *reinterpret_cast<const float4*>(
                &A[(size_t)(row0 + ar) * K + k0 + ak]);
            As[ak + 0][ar] = v.x;
            As[ak + 1][ar] = v.y;
            As[ak + 2][ar] = v.z;
            As[ak + 3][ar] = v.w;
        }
        // ---- B tile: 16 k x 64 cols ----
        {
            const int i  = tid * 4;
            const int bk = i >> 6;       // 0..15
            const int bc = i & 63;       // 0,4,...,60
            const int cg = col0 + bc;
            float4 v;
            if (EPI == 0) {
                v = *reinterpret_cast<const float4*>(
                    &B0[(size_t)(k0 + bk) * N + cg]);
            } else {
                if (cg < NQ)
                    v = *reinterpret_cast<const float4*>(
                        &B0[(size_t)(k0 + bk) * NQ + cg]);
                else if (cg < NQ + NKVD)
                    v = *reinterpret_cast<const float4*>(
                        &B1[(size_t)(k0 + bk) * NKVD + (cg - NQ)]);
                else
                    v = *reinterpret_cast<const float4*>(
                        &B2[(size_t)(k0 + bk) * NKVD + (cg - NQ - NKVD)]);
            }
            *reinterpret_cast<float4*>(&Bs[bk][bc]) = v;
        }
        __syncthreads();

        #pragma unroll
        for (int kk = 0; kk < 16; ++kk) {
            float4 a4 = *reinterpret_cast<const float4*>(&As[kk][ty * 4]);
            float4 b4 = *reinterpret_cast<const float4*>(&Bs[kk][tx * 4]);
            float a[4] = {a4.x, a4.y, a4.z, a4.w};
            float b[4] = {b4.x, b4.y, b4.z, b4.w};
            #pragma unroll
            for (int ii = 0; ii < 4; ++ii)
                #pragma unroll
                for (int jj = 0; jj < 4; ++jj)
                    acc[ii][jj] = fmaf(a[ii], b[jj], acc[ii][jj]);
        }
        __syncthreads();
    }

    // ---- epilogue ----
    const int cg0 = col0 + tx * 4;
    #pragma unroll
    for (int ii = 0; ii < 4; ++ii) {
        const int r = row0 + ty * 4 + ii;
        if (EPI == 0) {
            float4 v = {acc[ii][0], acc[ii][1], acc[ii][2], acc[ii][3]};
            *reinterpret_cast<float4*>(&C0[(size_t)r * N + cg0]) = v;
        } else {
            const int t = r & (TSEQ - 1);   // position within sequence
            if (cg0 < NQ + NKVD) {
                // RoPE on q / k. cg0 is 4-aligned -> two (even,odd) pairs.
                // (960 % 64 == 0, so cg0 & 63 is the head-local d for both.)
                const int d  = cg0 & (HD - 1);
                const int j0 = d >> 1;
                const float c0v = fcos[t * 32 + j0];
                const float s0v = fsin[t * 32 + j0];
                const float c1v = fcos[t * 32 + j0 + 1];
                const float s1v = fsin[t * 32 + j0 + 1];
                const float o0 = acc[ii][0] * c0v - acc[ii][1] * s0v;
                const float o1 = acc[ii][0] * s0v + acc[ii][1] * c0v;
                const float o2 = acc[ii][2] * c1v - acc[ii][3] * s1v;
                const float o3 = acc[ii][2] * s1v + acc[ii][3] * c1v;
                float4 v = {o0, o1, o2, o3};
                if (cg0 < NQ)
                    *reinterpret_cast<float4*>(&C0[(size_t)r * NQ + cg0]) = v;
                else
                    *reinterpret_cast<float4*>(&C1[(size_t)r * NKVD + (cg0 - NQ)]) = v;
            } else {
                float4 v = {acc[ii][0], acc[ii][1], acc[ii][2], acc[ii][3]};
                *reinterpret_cast<float4*>(&C2[(size_t)r * NKVD + (cg0 - NQ - NKVD)]) = v;
            }
        }
    }
}

// ---------------------------------------------------------------------------
// Flash-style causal attention, fp32 on VALU.
// Block = 256 threads = one (b, head, 64-row Q tile).
// Thread (r = tid/4, cq = (tid&3)*16): owns S row r cols [cq,cq+16) and
// O row r dims [cq,cq+16). K and V share one LDS buffer (loaded twice).
// ---------------------------------------------------------------------------
__global__ __launch_bounds__(256)
void attn_kernel(const float* __restrict__ q,
                 const float* __restrict__ k,
                 const float* __restrict__ v,
                 float* __restrict__ o)
{
    __shared__ float Qs[64][66];
    __shared__ float KVs[64][66];
    __shared__ float Ps[64][66];

    const int qt  = blockIdx.x;
    const int h   = blockIdx.y;
    const int b   = blockIdx.z;
    const int kvh = h / GQ;
    const int tid = threadIdx.x;
    const int r   = tid >> 2;          // 0..63
    const int cq  = (tid & 3) << 4;    // 0,16,32,48

    const int q0 = qt * 64;

    for (int i = tid; i < 64 * HD; i += 256) {
        const int rr = i >> 6, dd = i & 63;
        Qs[rr][dd] = q[((size_t)(b * TSEQ + q0 + rr) * NH + h) * HD + dd];
    }

    float m = -INFINITY, l = 0.f;
    float acc[16];
    #pragma unroll
    for (int i = 0; i < 16; ++i) acc[i] = 0.f;

    const int ntiles = qt + 1;   // causal: only tiles at or before diagonal
    for (int kt = 0; kt < ntiles; ++kt) {
        const int k0 = kt * 64;

        __syncthreads();   // previous iteration done with KVs / Ps
        for (int i = tid; i < 64 * HD; i += 256) {
            const int rr = i >> 6, dd = i & 63;
            KVs[rr][dd] = k[((size_t)(b * TSEQ + k0 + rr) * NKV + kvh) * HD + dd];
        }
        __syncthreads();

        // S = Q K^T * scale (row r, 16 cols)
        float s[16];
        #pragma unroll
        for (int c = 0; c < 16; ++c) s[c] = 0.f;
        for (int d = 0; d < HD; ++d) {
            const float qd = Qs[r][d];
            #pragma unroll
            for (int c = 0; c < 16; ++c)
                s[c] = fmaf(qd, KVs[cq + c][d], s[c]);
        }

        float mt = -INFINITY;
        #pragma unroll
        for (int c = 0; c < 16; ++c) {
            s[c] *= 0.125f;                            // 1/sqrt(64)
            if (k0 + cq + c > q0 + r) s[c] = -INFINITY; // causal mask
            mt = fmaxf(mt, s[c]);
        }
        mt = fmaxf(mt, __shfl_xor(mt, 1, 64));
        mt = fmaxf(mt, __shfl_xor(mt, 2, 64));
        const float mnew = fmaxf(m, mt);
        const float corr = __expf(m - mnew);   // m=-inf first iter -> 0

        float lsum = 0.f;
        #pragma unroll
        for (int c = 0; c < 16; ++c) {
            const float p = __expf(s[c] - mnew);
            Ps[r][cq + c] = p;
            lsum += p;
        }
        lsum += __shfl_xor(lsum, 1, 64);
        lsum += __shfl_xor(lsum, 2, 64);
        l = l * corr + lsum;
        m = mnew;
        #pragma unroll
        for (int i = 0; i < 16; ++i) acc[i] *= corr;

        __syncthreads();   // Ps written, S-phase reads of KVs done
        for (int i = tid; i < 64 * HD; i += 256) {
            const int rr = i >> 6, dd = i & 63;
            KVs[rr][dd] = v[((size_t)(b * TSEQ + k0 + rr) * NKV + kvh) * HD + dd];
        }
        __syncthreads();

        // O += P V  (row r, dims [cq, cq+16))
        for (int c = 0; c < 64; ++c) {
            const float p = Ps[r][c];
            #pragma unroll
            for (int d = 0; d < 16; ++d)
                acc[d] = fmaf(p, KVs[c][cq + d], acc[d]);
        }
    }

    const float inv = 1.0f / l;
    #pragma unroll
    for (int d = 0; d < 16; ++d)
        o[((size_t)(b * TSEQ + q0 + r) * NH + h) * HD + cq + d] = acc[d] * inv;
}

// ---------------------------------------------------------------------------
extern "C" void kernel_launch(void* const* d_in, const int* in_sizes, int n_in,
                              void* d_out, int out_size, void* d_ws, size_t ws_size,
                              hipStream_t stream)
{
    const float* x    = (const float*)d_in[0];
    const float* fcos = (const float*)d_in[1];
    const float* fsin = (const float*)d_in[2];
    const float* wq   = (const float*)d_in[3];
    const float* wk   = (const float*)d_in[4];
    const float* wv   = (const float*)d_in[5];
    const float* wo   = (const float*)d_in[6];
    float* out = (float*)d_out;

    const int M = BATCH * TSEQ;   // 8192 rows

    // workspace layout (fp32): q | k | v | attn_out  (~84 MB total)
    float* qb = (float*)d_ws;
    float* kb = qb + (size_t)M * NQ;
    float* vb = kb + (size_t)M * NKVD;
    float* ao = vb + (size_t)M * NKVD;

    dim3 blk(256);

    // fused QKV projection + RoPE
    gemm64<1><<<dim3(NTOT / 64, M / 64), blk, 0, stream>>>(
        x, wq, wk, wv, qb, kb, vb, fcos, fsin, M, NTOT, DIM);

    // causal flash attention
    attn_kernel<<<dim3(TSEQ / 64, NH, BATCH), blk, 0, stream>>>(qb, kb, vb, ao);

    // output projection
    gemm64<0><<<dim3(DIM / 64, M / 64), blk, 0, stream>>>(
        ao, wo, nullptr, nullptr, out, nullptr, nullptr, nullptr, nullptr,
        M, DIM, DIM);
}

// Round 2
// 925.826 us; speedup vs baseline: 4.4969x; 4.4969x over previous
//
#include <hip/hip_runtime.h>
#include <hip/hip_bf16.h>
#include <cmath>

#define DIM  960
#define NH   15
#define NKV  5
#define HD   64
#define GQ   3          // NH / NKV
#define TSEQ 2048
#define BATCH 4
#define NQ   (NH * HD)        // 960
#define NKVD (NKV * HD)       // 320
#define NTOT (NQ + 2 * NKVD)  // 1600

using bf16x8 = __attribute__((ext_vector_type(8))) short;
using f32x4  = __attribute__((ext_vector_type(4))) float;

static __device__ __forceinline__ ushort f2bf(float f) {
    __hip_bfloat16 h = __float2bfloat16(f);
    return *reinterpret_cast<ushort*>(&h);
}

// ---------------------------------------------------------------------------
// Tiled fp32 GEMM: C = A(MxK) @ B(KxN). 64x64 tile, BK=16, 256 threads,
// 4x4 microtile. EPI==1: fused QKV projection + RoPE epilogue, bf16 outputs
// (q,k,v). EPI==0: plain fp32 store.
// ---------------------------------------------------------------------------
template<int EPI>
__global__ __launch_bounds__(256)
void gemm64(const float* __restrict__ A,
            const float* __restrict__ B0,
            const float* __restrict__ B1,
            const float* __restrict__ B2,
            float* __restrict__ Cf,
            ushort* __restrict__ Cq,
            ushort* __restrict__ Ck,
            ushort* __restrict__ Cv,
            const float* __restrict__ fcos,
            const float* __restrict__ fsin,
            int M, int N, int K)
{
    __shared__ float As[16][68];
    __shared__ float Bs[16][68];

    const int row0 = blockIdx.y * 64;
    const int col0 = blockIdx.x * 64;
    const int tid  = threadIdx.x;
    const int ty   = tid >> 4;
    const int tx   = tid & 15;

    float acc[4][4] = {};

    for (int k0 = 0; k0 < K; k0 += 16) {
        {
            const int i  = tid * 4;
            const int ar = i >> 4;
            const int ak = i & 15;
            float4 v = *reinterpret_cast<const float4*>(
                &A[(size_t)(row0 + ar) * K + k0 + ak]);
            As[ak + 0][ar] = v.x;
            As[ak + 1][ar] = v.y;
            As[ak + 2][ar] = v.z;
            As[ak + 3][ar] = v.w;
        }
        {
            const int i  = tid * 4;
            const int bk = i >> 6;
            const int bc = i & 63;
            const int cg = col0 + bc;
            float4 v;
            if (EPI == 0) {
                v = *reinterpret_cast<const float4*>(
                    &B0[(size_t)(k0 + bk) * N + cg]);
            } else {
                if (cg < NQ)
                    v = *reinterpret_cast<const float4*>(
                        &B0[(size_t)(k0 + bk) * NQ + cg]);
                else if (cg < NQ + NKVD)
                    v = *reinterpret_cast<const float4*>(
                        &B1[(size_t)(k0 + bk) * NKVD + (cg - NQ)]);
                else
                    v = *reinterpret_cast<const float4*>(
                        &B2[(size_t)(k0 + bk) * NKVD + (cg - NQ - NKVD)]);
            }
            *reinterpret_cast<float4*>(&Bs[bk][bc]) = v;
        }
        __syncthreads();

        #pragma unroll
        for (int kk = 0; kk < 16; ++kk) {
            float4 a4 = *reinterpret_cast<const float4*>(&As[kk][ty * 4]);
            float4 b4 = *reinterpret_cast<const float4*>(&Bs[kk][tx * 4]);
            float a[4] = {a4.x, a4.y, a4.z, a4.w};
            float b[4] = {b4.x, b4.y, b4.z, b4.w};
            #pragma unroll
            for (int ii = 0; ii < 4; ++ii)
                #pragma unroll
                for (int jj = 0; jj < 4; ++jj)
                    acc[ii][jj] = fmaf(a[ii], b[jj], acc[ii][jj]);
        }
        __syncthreads();
    }

    const int cg0 = col0 + tx * 4;
    #pragma unroll
    for (int ii = 0; ii < 4; ++ii) {
        const int r = row0 + ty * 4 + ii;
        if (EPI == 0) {
            float4 v = {acc[ii][0], acc[ii][1], acc[ii][2], acc[ii][3]};
            *reinterpret_cast<float4*>(&Cf[(size_t)r * N + cg0]) = v;
        } else {
            const int t = r & (TSEQ - 1);
            if (cg0 < NQ + NKVD) {
                // RoPE (fp32), then round to bf16
                const int d  = cg0 & (HD - 1);
                const int j0 = d >> 1;
                const float c0v = fcos[t * 32 + j0];
                const float s0v = fsin[t * 32 + j0];
                const float c1v = fcos[t * 32 + j0 + 1];
                const float s1v = fsin[t * 32 + j0 + 1];
                ushort4 pk;
                pk.x = f2bf(acc[ii][0] * c0v - acc[ii][1] * s0v);
                pk.y = f2bf(acc[ii][0] * s0v + acc[ii][1] * c0v);
                pk.z = f2bf(acc[ii][2] * c1v - acc[ii][3] * s1v);
                pk.w = f2bf(acc[ii][2] * s1v + acc[ii][3] * c1v);
                if (cg0 < NQ)
                    *reinterpret_cast<ushort4*>(&Cq[(size_t)r * NQ + cg0]) = pk;
                else
                    *reinterpret_cast<ushort4*>(&Ck[(size_t)r * NKVD + (cg0 - NQ)]) = pk;
            } else {
                ushort4 pk;
                pk.x = f2bf(acc[ii][0]);
                pk.y = f2bf(acc[ii][1]);
                pk.z = f2bf(acc[ii][2]);
                pk.w = f2bf(acc[ii][3]);
                *reinterpret_cast<ushort4*>(&Cv[(size_t)r * NKVD + (cg0 - NQ - NKVD)]) = pk;
            }
        }
    }
}

// ---------------------------------------------------------------------------
// Flash attention, bf16 MFMA (16x16x32). Block = 4 waves = 64 Q rows.
// Per wave: 16 Q rows. K-tile = 64 keys.
// LDS: K [64 rows][64 d] bf16 swizzled; V^T [64 d][64 keys] bf16 swizzled;
//      P per-wave [16 rows][64 keys] bf16 swizzled. XOR swizzle:
//      byte ^= (row&7)<<4 (row stride = 128 B).
// MFMA layouts (guide-verified): A: lane holds A[l&15][(l>>4)*8+j];
// B: lane holds B[(l>>4)*8+j][l&15]; C/D: col=l&15, row=(l>>4)*4+reg.
// ---------------------------------------------------------------------------
__global__ __launch_bounds__(256)
void attn_mfma(const ushort* __restrict__ qh,
               const ushort* __restrict__ kh,
               const ushort* __restrict__ vh,
               float* __restrict__ ao)
{
    __shared__ char lds[24 * 1024];
    char* Klds = lds;                    // 8 KB
    char* Vlds = lds + 8192;             // 8 KB (V^T)
    char* Plds = lds + 16384;            // 4 x 2 KB per wave

    const int qt  = blockIdx.x;
    const int h   = blockIdx.y;
    const int b   = blockIdx.z;
    const int kvh = h / GQ;
    const int tid  = threadIdx.x;
    const int wave = tid >> 6;
    const int lane = tid & 63;
    const int lr   = lane & 15;
    const int lg   = lane >> 4;
    const int q0   = qt * 64;

    char* Pw = Plds + wave * 2048;

    // Q fragments: rows q0+wave*16+lr, k-halves 0..31 / 32..63
    bf16x8 qf[2];
    {
        const ushort* qp = qh + ((size_t)(b * TSEQ + q0 + wave * 16 + lr) * NH + h) * HD;
        qf[0] = *reinterpret_cast<const bf16x8*>(qp + lg * 8);
        qf[1] = *reinterpret_cast<const bf16x8*>(qp + 32 + lg * 8);
    }

    f32x4 O[4];
    float m[4], l[4];
    #pragma unroll
    for (int dt = 0; dt < 4; ++dt) O[dt] = f32x4{0.f, 0.f, 0.f, 0.f};
    #pragma unroll
    for (int r = 0; r < 4; ++r) { m[r] = -INFINITY; l[r] = 0.f; }

    for (int kt = 0; kt <= qt; ++kt) {
        const int k0 = kt * 64;

        __syncthreads();   // all waves done reading prev tile's K/V

        // ---- stage K: rows=keys, contiguous d, swizzled b128 writes ----
        #pragma unroll
        for (int it = 0; it < 2; ++it) {
            const int ci  = tid + it * 256;
            const int row = ci & 63;
            const int ch  = ci >> 6;          // 0..7 (16B chunk within row)
            bf16x8 kv = *reinterpret_cast<const bf16x8*>(
                kh + ((size_t)(b * TSEQ + k0 + row) * NKV + kvh) * HD + ch * 8);
            const int db = (row * 128 + ch * 16) ^ ((row & 7) << 4);
            *reinterpret_cast<bf16x8*>(Klds + db) = kv;
        }
        // ---- stage V^T: read V[key][d0..d0+7], scatter as [d][key] ----
        #pragma unroll
        for (int it = 0; it < 2; ++it) {
            const int ci   = tid + it * 256;
            const int key  = ci & 63;
            const int dblk = ci >> 6;         // 0..7
            bf16x8 vv = *reinterpret_cast<const bf16x8*>(
                vh + ((size_t)(b * TSEQ + k0 + key) * NKV + kvh) * HD + dblk * 8);
            #pragma unroll
            for (int j = 0; j < 8; ++j) {
                const int d  = dblk * 8 + j;
                const int db = (d * 128 + key * 2) ^ ((d & 7) << 4);
                *reinterpret_cast<ushort*>(Vlds + db) =
                    reinterpret_cast<const ushort*>(&vv)[j];
            }
        }
        __syncthreads();

        // ---- S = Q K^T : 4 col-tiles x 2 k-steps ----
        f32x4 s4[4];
        #pragma unroll
        for (int c = 0; c < 4; ++c) {
            f32x4 acc = f32x4{0.f, 0.f, 0.f, 0.f};
            #pragma unroll
            for (int ks = 0; ks < 2; ++ks) {
                const int row = c * 16 + lr;
                const int db  = (row * 128 + ks * 64 + lg * 16) ^ ((row & 7) << 4);
                bf16x8 kf = *reinterpret_cast<const bf16x8*>(Klds + db);
                acc = __builtin_amdgcn_mfma_f32_16x16x32_bf16(qf[ks], kf, acc, 0, 0, 0);
            }
            s4[c] = acc;
        }

        // ---- online softmax (rows = lg*4+reg, col = c*16+lr) ----
        const bool diag = (kt == qt);
        float sv[4][4];
        float mt[4];
        #pragma unroll
        for (int reg = 0; reg < 4; ++reg) mt[reg] = -INFINITY;
        #pragma unroll
        for (int reg = 0; reg < 4; ++reg) {
            const int qrow = q0 + wave * 16 + lg * 4 + reg;
            #pragma unroll
            for (int c = 0; c < 4; ++c) {
                float x = s4[c][reg] * 0.125f;
                if (diag && (k0 + c * 16 + lr > qrow)) x = -INFINITY;
                sv[c][reg] = x;
                mt[reg] = fmaxf(mt[reg], x);
            }
        }
        #pragma unroll
        for (int reg = 0; reg < 4; ++reg) {
            float v = mt[reg];
            v = fmaxf(v, __shfl_xor(v, 1));
            v = fmaxf(v, __shfl_xor(v, 2));
            v = fmaxf(v, __shfl_xor(v, 4));
            v = fmaxf(v, __shfl_xor(v, 8));
            const float mn   = fmaxf(m[reg], v);
            const float corr = __expf(m[reg] - mn);   // 0 on first tile
            m[reg] = mn;
            float ls = 0.f;
            const int prow = lg * 4 + reg;
            #pragma unroll
            for (int c = 0; c < 4; ++c) {
                const float p = __expf(sv[c][reg] - mn);
                ls += p;
                const int db = (prow * 128 + (c * 16 + lr) * 2) ^ ((prow & 7) << 4);
                *reinterpret_cast<ushort*>(Pw + db) = f2bf(p);
            }
            ls += __shfl_xor(ls, 1);
            ls += __shfl_xor(ls, 2);
            ls += __shfl_xor(ls, 4);
            ls += __shfl_xor(ls, 8);
            l[reg] = l[reg] * corr + ls;
            #pragma unroll
            for (int dt = 0; dt < 4; ++dt) O[dt][reg] *= corr;
        }

        // P writes are per-wave; drain LDS before re-reading as fragments
        asm volatile("s_waitcnt lgkmcnt(0)" ::: "memory");

        // ---- O += P V : A = P frags (2 k-steps), B = V^T frags ----
        bf16x8 pf[2];
        #pragma unroll
        for (int ks = 0; ks < 2; ++ks) {
            const int db = (lr * 128 + ks * 64 + lg * 16) ^ ((lr & 7) << 4);
            pf[ks] = *reinterpret_cast<const bf16x8*>(Pw + db);
        }
        #pragma unroll
        for (int dt = 0; dt < 4; ++dt) {
            #pragma unroll
            for (int ks = 0; ks < 2; ++ks) {
                const int row = dt * 16 + lr;
                const int db  = (row * 128 + ks * 64 + lg * 16) ^ ((row & 7) << 4);
                bf16x8 vf = *reinterpret_cast<const bf16x8*>(Vlds + db);
                O[dt] = __builtin_amdgcn_mfma_f32_16x16x32_bf16(pf[ks], vf, O[dt], 0, 0, 0);
            }
        }
    }

    // ---- epilogue: O / l -> ao (fp32, [M][960]) ----
    #pragma unroll
    for (int reg = 0; reg < 4; ++reg) {
        const float inv = 1.f / l[reg];
        const int r = q0 + wave * 16 + lg * 4 + reg;
        #pragma unroll
        for (int dt = 0; dt < 4; ++dt) {
            ao[(size_t)(b * TSEQ + r) * NQ + h * HD + dt * 16 + lr] = O[dt][reg] * inv;
        }
    }
}

// ---------------------------------------------------------------------------
extern "C" void kernel_launch(void* const* d_in, const int* in_sizes, int n_in,
                              void* d_out, int out_size, void* d_ws, size_t ws_size,
                              hipStream_t stream)
{
    const float* x    = (const float*)d_in[0];
    const float* fcos = (const float*)d_in[1];
    const float* fsin = (const float*)d_in[2];
    const float* wq   = (const float*)d_in[3];
    const float* wk   = (const float*)d_in[4];
    const float* wv   = (const float*)d_in[5];
    const float* wo   = (const float*)d_in[6];
    float* out = (float*)d_out;

    const int M = BATCH * TSEQ;   // 8192

    // workspace: qh bf16 | kh bf16 | vh bf16 | ao fp32  (~58 MB)
    ushort* qhb = (ushort*)d_ws;
    ushort* khb = qhb + (size_t)M * NQ;
    ushort* vhb = khb + (size_t)M * NKVD;
    float*  ao  = (float*)(vhb + (size_t)M * NKVD);

    dim3 blk(256);

    // fused QKV projection + RoPE + bf16 cast
    gemm64<1><<<dim3(NTOT / 64, M / 64), blk, 0, stream>>>(
        x, wq, wk, wv, nullptr, qhb, khb, vhb, fcos, fsin, M, NTOT, DIM);

    // causal flash attention (bf16 MFMA, fp32 softmax/accum)
    attn_mfma<<<dim3(TSEQ / 64, NH, BATCH), blk, 0, stream>>>(qhb, khb, vhb, ao);

    // output projection (fp32)
    gemm64<0><<<dim3(DIM / 64, M / 64), blk, 0, stream>>>(
        ao, wo, nullptr, nullptr, out, nullptr, nullptr, nullptr, nullptr, nullptr,
        M, DIM, DIM);
}

// Round 3
// 464.989 us; speedup vs baseline: 8.9536x; 1.9911x over previous
//
#include <hip/hip_runtime.h>
#include <hip/hip_bf16.h>
#include <cmath>

#define DIM  960
#define NH   15
#define NKV  5
#define HD   64
#define GQ   3
#define TSEQ 2048
#define BATCH 4
#define NQ   (NH * HD)        // 960
#define NKVD (NKV * HD)       // 320
#define NTOT (NQ + 2 * NKVD)  // 1600
#define NTOT_PAD 1664         // 13 * 128
#define NO_PAD   1024         // 8 * 128

using bf16x8 = __attribute__((ext_vector_type(8))) short;
using f32x4  = __attribute__((ext_vector_type(4))) float;

static __device__ __forceinline__ ushort f2bf(float f) {
    __hip_bfloat16 h = __float2bfloat16(f);
    return *reinterpret_cast<ushort*>(&h);
}

typedef const __attribute__((address_space(1))) unsigned char* gp_t;
typedef __attribute__((address_space(3))) unsigned char* lp_t;

static __device__ __forceinline__ void gload_lds16(const void* g, void* l) {
    // LDS dest = wave-uniform base + lane*16 (m104); pass uniform base.
    __builtin_amdgcn_global_load_lds((gp_t)g, (lp_t)l, 16, 0, 0);
}

// ---------------------------------------------------------------------------
// x fp32 -> bf16
// ---------------------------------------------------------------------------
__global__ __launch_bounds__(256)
void cvt_x(const float* __restrict__ x, ushort* __restrict__ xb, int n4)
{
    int i = blockIdx.x * blockDim.x + threadIdx.x;
    const int stride = gridDim.x * blockDim.x;
    for (; i < n4; i += stride) {
        float4 v = reinterpret_cast<const float4*>(x)[i];
        ushort4 o = {f2bf(v.x), f2bf(v.y), f2bf(v.z), f2bf(v.w)};
        reinterpret_cast<ushort4*>(xb)[i] = o;
    }
}

// ---------------------------------------------------------------------------
// Weight transpose + bf16 convert. src [960][ncols] fp32 -> dst[dstoff+c][k] bf16.
// z: 0=wq, 1=wk, 2=wv (-> wqkvT), 3=wo (-> woT)
// ---------------------------------------------------------------------------
__global__ __launch_bounds__(256)
void transpose_wb(const float* __restrict__ wq, const float* __restrict__ wk,
                  const float* __restrict__ wv, const float* __restrict__ wo,
                  ushort* __restrict__ wqkvT, ushort* __restrict__ woT)
{
    __shared__ float tile[32][33];
    const float* src; ushort* dst; int ncols, dstoff;
    switch (blockIdx.z) {
        case 0:  src = wq; ncols = NQ;   dst = wqkvT; dstoff = 0;    break;
        case 1:  src = wk; ncols = NKVD; dst = wqkvT; dstoff = NQ;   break;
        case 2:  src = wv; ncols = NKVD; dst = wqkvT; dstoff = NQ + NKVD; break;
        default: src = wo; ncols = NQ;   dst = woT;   dstoff = 0;    break;
    }
    const int c0 = blockIdx.x * 32;
    if (c0 >= ncols) return;
    const int k0 = blockIdx.y * 32;
    const int tx = threadIdx.x & 31, ty = threadIdx.x >> 5;
    #pragma unroll
    for (int i = 0; i < 4; ++i)
        tile[ty * 4 + i][tx] = src[(size_t)(k0 + ty * 4 + i) * ncols + c0 + tx];
    __syncthreads();
    #pragma unroll
    for (int i = 0; i < 4; ++i) {
        const int c = c0 + ty * 4 + i;
        dst[(size_t)(dstoff + c) * DIM + k0 + tx] = f2bf(tile[tx][ty * 4 + i]);
    }
}

// ---------------------------------------------------------------------------
// bf16 MFMA GEMM, m97-style: 128x128 tile, BK=32, 256 thr (4 waves 2x2),
// each wave 64x64 = 4x4 frags. Double-buffered LDS via global_load_lds w=16.
// LDS per buf: A[128 rows][32 k] + BT[128 cols][32 k], 64 B/row, chunk-XOR
// swizzle: read chunk = lg ^ ((row>>1)&3)  (2-way conflict = free, m136);
// staging pre-applies the inverse on the GLOBAL source (rule #21).
// EPI==1: QKV + RoPE epilogue (bf16 q/k/v). EPI==0: fp32 C store.
// ---------------------------------------------------------------------------
template<int EPI>
__global__ __launch_bounds__(256)
void gemm_mfma(const ushort* __restrict__ A,    // [M][K] bf16
               const ushort* __restrict__ BT,   // [Npad][K] bf16
               ushort* __restrict__ Cq, ushort* __restrict__ Ck,
               ushort* __restrict__ Cv, float* __restrict__ Cf,
               const float* __restrict__ fcos, const float* __restrict__ fsin,
               int K, int NT)                    // NT = K/32
{
    __shared__ char lds[32 * 1024];

    const int tid  = threadIdx.x;
    const int wave = tid >> 6;
    const int lane = tid & 63;
    const int lr   = lane & 15;
    const int lg   = lane >> 4;
    const int wr   = wave >> 1;       // 0..1
    const int wc   = wave & 1;        // 0..1
    const int row0 = blockIdx.y * 128;
    const int col0 = blockIdx.x * 128;

    const int swz = ((lr >> 1) & 3) << 4;   // read-side chunk XOR (bytes)

    f32x4 acc[4][4];
    #pragma unroll
    for (int mi = 0; mi < 4; ++mi)
        #pragma unroll
        for (int ni = 0; ni < 4; ++ni)
            acc[mi][ni] = f32x4{0.f, 0.f, 0.f, 0.f};

    // staging indices (per thread, k0-independent)
    const int sr  = lane >> 2;        // row within 16-row chunk
    const int scp = lane & 3;         // 16B chunk position in row

    auto stage = [&](int t, int bufsel) {
        const int k0 = t * 32;
        char* Ab = lds + bufsel * 16384;
        char* Bb = Ab + 8192;
        #pragma unroll
        for (int i = 0; i < 2; ++i) {
            const int r0 = (wave * 2 + i) * 16;
            const int r  = r0 + sr;
            const int gc = scp ^ ((r >> 1) & 3);
            gload_lds16(A + (size_t)(row0 + r) * K + k0 + gc * 8, Ab + r0 * 64);
        }
        #pragma unroll
        for (int i = 0; i < 2; ++i) {
            const int r0 = (wave * 2 + i) * 16;
            const int r  = r0 + sr;
            const int gc = scp ^ ((r >> 1) & 3);
            gload_lds16(BT + (size_t)(col0 + r) * K + k0 + gc * 8, Bb + r0 * 64);
        }
    };

    auto compute = [&](int bufsel) {
        char* Ab = lds + bufsel * 16384;
        char* Bb = Ab + 8192;
        bf16x8 af[4], bfr[4];
        #pragma unroll
        for (int mi = 0; mi < 4; ++mi)
            af[mi] = *reinterpret_cast<const bf16x8*>(
                Ab + (wr * 64 + mi * 16 + lr) * 64 + (lg * 16 ^ swz));
        #pragma unroll
        for (int ni = 0; ni < 4; ++ni)
            bfr[ni] = *reinterpret_cast<const bf16x8*>(
                Bb + (wc * 64 + ni * 16 + lr) * 64 + (lg * 16 ^ swz));
        #pragma unroll
        for (int mi = 0; mi < 4; ++mi)
            #pragma unroll
            for (int ni = 0; ni < 4; ++ni)
                acc[mi][ni] = __builtin_amdgcn_mfma_f32_16x16x32_bf16(
                    af[mi], bfr[ni], acc[mi][ni], 0, 0, 0);
    };

    stage(0, 0);
    __syncthreads();                       // drains vmcnt (graph: syncthreads waits vmcnt(0))
    for (int t = 0; t < NT; ++t) {
        if (t + 1 < NT) stage(t + 1, (t & 1) ^ 1);
        compute(t & 1);
        __syncthreads();
    }

    // ---- epilogue ----
    #pragma unroll
    for (int mi = 0; mi < 4; ++mi) {
        #pragma unroll
        for (int q = 0; q < 4; ++q) {
            const int row = row0 + wr * 64 + mi * 16 + lg * 4 + q;
            const int t   = row & (TSEQ - 1);
            #pragma unroll
            for (int ni = 0; ni < 4; ++ni) {
                const float vv = acc[mi][ni][q];
                const int col = col0 + wc * 64 + ni * 16 + lr;
                if (EPI == 0) {
                    if (col < DIM)
                        Cf[(size_t)row * DIM + col] = vv;
                } else {
                    const float pv = __shfl_xor(vv, 1);   // RoPE partner (all lanes active)
                    if (col < NQ + NKVD) {
                        const int j = (col & (HD - 1)) >> 1;
                        const float c = fcos[t * 32 + j];
                        const float s = fsin[t * 32 + j];
                        const float ov = (lr & 1) ? (pv * s + vv * c)
                                                  : (vv * c - pv * s);
                        if (col < NQ)
                            Cq[(size_t)row * NQ + col] = f2bf(ov);
                        else
                            Ck[(size_t)row * NKVD + (col - NQ)] = f2bf(ov);
                    } else if (col < NTOT) {
                        Cv[(size_t)row * NKVD + (col - NQ - NKVD)] = f2bf(vv);
                    }
                }
            }
        }
    }
}

// ---------------------------------------------------------------------------
// Flash attention, bf16 MFMA (16x16x32). Unchanged from round 2 except:
// bf16 output (feeds outproj directly) and s_setprio around MFMA clusters.
// ---------------------------------------------------------------------------
__global__ __launch_bounds__(256)
void attn_mfma(const ushort* __restrict__ qh,
               const ushort* __restrict__ kh,
               const ushort* __restrict__ vh,
               ushort* __restrict__ ao)
{
    __shared__ char lds[24 * 1024];
    char* Klds = lds;
    char* Vlds = lds + 8192;
    char* Plds = lds + 16384;

    const int qt  = blockIdx.x;
    const int h   = blockIdx.y;
    const int b   = blockIdx.z;
    const int kvh = h / GQ;
    const int tid  = threadIdx.x;
    const int wave = tid >> 6;
    const int lane = tid & 63;
    const int lr   = lane & 15;
    const int lg   = lane >> 4;
    const int q0   = qt * 64;

    char* Pw = Plds + wave * 2048;

    bf16x8 qf[2];
    {
        const ushort* qp = qh + ((size_t)(b * TSEQ + q0 + wave * 16 + lr) * NH + h) * HD;
        qf[0] = *reinterpret_cast<const bf16x8*>(qp + lg * 8);
        qf[1] = *reinterpret_cast<const bf16x8*>(qp + 32 + lg * 8);
    }

    f32x4 O[4];
    float m[4], l[4];
    #pragma unroll
    for (int dt = 0; dt < 4; ++dt) O[dt] = f32x4{0.f, 0.f, 0.f, 0.f};
    #pragma unroll
    for (int r = 0; r < 4; ++r) { m[r] = -INFINITY; l[r] = 0.f; }

    for (int kt = 0; kt <= qt; ++kt) {
        const int k0 = kt * 64;

        __syncthreads();

        #pragma unroll
        for (int it = 0; it < 2; ++it) {
            const int ci  = tid + it * 256;
            const int row = ci & 63;
            const int ch  = ci >> 6;
            bf16x8 kv = *reinterpret_cast<const bf16x8*>(
                kh + ((size_t)(b * TSEQ + k0 + row) * NKV + kvh) * HD + ch * 8);
            const int db = (row * 128 + ch * 16) ^ ((row & 7) << 4);
            *reinterpret_cast<bf16x8*>(Klds + db) = kv;
        }
        #pragma unroll
        for (int it = 0; it < 2; ++it) {
            const int ci   = tid + it * 256;
            const int key  = ci & 63;
            const int dblk = ci >> 6;
            bf16x8 vv = *reinterpret_cast<const bf16x8*>(
                vh + ((size_t)(b * TSEQ + k0 + key) * NKV + kvh) * HD + dblk * 8);
            #pragma unroll
            for (int j = 0; j < 8; ++j) {
                const int d  = dblk * 8 + j;
                const int db = (d * 128 + key * 2) ^ ((d & 7) << 4);
                *reinterpret_cast<ushort*>(Vlds + db) =
                    reinterpret_cast<const ushort*>(&vv)[j];
            }
        }
        __syncthreads();

        f32x4 s4[4];
        __builtin_amdgcn_s_setprio(1);
        #pragma unroll
        for (int c = 0; c < 4; ++c) {
            f32x4 acc = f32x4{0.f, 0.f, 0.f, 0.f};
            #pragma unroll
            for (int ks = 0; ks < 2; ++ks) {
                const int row = c * 16 + lr;
                const int db  = (row * 128 + ks * 64 + lg * 16) ^ ((row & 7) << 4);
                bf16x8 kf = *reinterpret_cast<const bf16x8*>(Klds + db);
                acc = __builtin_amdgcn_mfma_f32_16x16x32_bf16(qf[ks], kf, acc, 0, 0, 0);
            }
            s4[c] = acc;
        }
        __builtin_amdgcn_s_setprio(0);

        const bool diag = (kt == qt);
        float sv[4][4];
        float mt[4];
        #pragma unroll
        for (int reg = 0; reg < 4; ++reg) mt[reg] = -INFINITY;
        #pragma unroll
        for (int reg = 0; reg < 4; ++reg) {
            const int qrow = q0 + wave * 16 + lg * 4 + reg;
            #pragma unroll
            for (int c = 0; c < 4; ++c) {
                float x = s4[c][reg] * 0.125f;
                if (diag && (k0 + c * 16 + lr > qrow)) x = -INFINITY;
                sv[c][reg] = x;
                mt[reg] = fmaxf(mt[reg], x);
            }
        }
        #pragma unroll
        for (int reg = 0; reg < 4; ++reg) {
            float v = mt[reg];
            v = fmaxf(v, __shfl_xor(v, 1));
            v = fmaxf(v, __shfl_xor(v, 2));
            v = fmaxf(v, __shfl_xor(v, 4));
            v = fmaxf(v, __shfl_xor(v, 8));
            const float mn   = fmaxf(m[reg], v);
            const float corr = __expf(m[reg] - mn);
            m[reg] = mn;
            float ls = 0.f;
            const int prow = lg * 4 + reg;
            #pragma unroll
            for (int c = 0; c < 4; ++c) {
                const float p = __expf(sv[c][reg] - mn);
                ls += p;
                const int db = (prow * 128 + (c * 16 + lr) * 2) ^ ((prow & 7) << 4);
                *reinterpret_cast<ushort*>(Pw + db) = f2bf(p);
            }
            ls += __shfl_xor(ls, 1);
            ls += __shfl_xor(ls, 2);
            ls += __shfl_xor(ls, 4);
            ls += __shfl_xor(ls, 8);
            l[reg] = l[reg] * corr + ls;
            #pragma unroll
            for (int dt = 0; dt < 4; ++dt) O[dt][reg] *= corr;
        }

        asm volatile("s_waitcnt lgkmcnt(0)" ::: "memory");
        __builtin_amdgcn_sched_barrier(0);   // rule 18: keep MFMA below the wait

        bf16x8 pf[2];
        #pragma unroll
        for (int ks = 0; ks < 2; ++ks) {
            const int db = (lr * 128 + ks * 64 + lg * 16) ^ ((lr & 7) << 4);
            pf[ks] = *reinterpret_cast<const bf16x8*>(Pw + db);
        }
        __builtin_amdgcn_s_setprio(1);
        #pragma unroll
        for (int dt = 0; dt < 4; ++dt) {
            #pragma unroll
            for (int ks = 0; ks < 2; ++ks) {
                const int row = dt * 16 + lr;
                const int db  = (row * 128 + ks * 64 + lg * 16) ^ ((row & 7) << 4);
                bf16x8 vf = *reinterpret_cast<const bf16x8*>(Vlds + db);
                O[dt] = __builtin_amdgcn_mfma_f32_16x16x32_bf16(pf[ks], vf, O[dt], 0, 0, 0);
            }
        }
        __builtin_amdgcn_s_setprio(0);
    }

    #pragma unroll
    for (int reg = 0; reg < 4; ++reg) {
        const float inv = 1.f / l[reg];
        const int r = q0 + wave * 16 + lg * 4 + reg;
        #pragma unroll
        for (int dt = 0; dt < 4; ++dt) {
            ao[(size_t)(b * TSEQ + r) * NQ + h * HD + dt * 16 + lr] =
                f2bf(O[dt][reg] * inv);
        }
    }
}

// ---------------------------------------------------------------------------
extern "C" void kernel_launch(void* const* d_in, const int* in_sizes, int n_in,
                              void* d_out, int out_size, void* d_ws, size_t ws_size,
                              hipStream_t stream)
{
    const float* x    = (const float*)d_in[0];
    const float* fcos = (const float*)d_in[1];
    const float* fsin = (const float*)d_in[2];
    const float* wq   = (const float*)d_in[3];
    const float* wk   = (const float*)d_in[4];
    const float* wv   = (const float*)d_in[5];
    const float* wo   = (const float*)d_in[6];
    float* out = (float*)d_out;

    const int M = BATCH * TSEQ;   // 8192

    // workspace (all bf16 except none): xb | wqkvT | woT | qb | kb | vb | ao
    ushort* xb    = (ushort*)d_ws;
    ushort* wqkvT = xb    + (size_t)M * DIM;
    ushort* woT   = wqkvT + (size_t)NTOT_PAD * DIM;
    ushort* qb    = woT   + (size_t)NO_PAD * DIM;
    ushort* kb    = qb    + (size_t)M * NQ;
    ushort* vb    = kb    + (size_t)M * NKVD;
    ushort* ao    = vb    + (size_t)M * NKVD;

    // prep: x -> bf16 ; weights -> transposed bf16
    cvt_x<<<2048, 256, 0, stream>>>(x, xb, M * DIM / 4);
    transpose_wb<<<dim3(30, 30, 4), 256, 0, stream>>>(wq, wk, wv, wo, wqkvT, woT);

    // QKV projection + RoPE (bf16 MFMA)
    gemm_mfma<1><<<dim3(NTOT_PAD / 128, M / 128), 256, 0, stream>>>(
        xb, wqkvT, qb, kb, vb, nullptr, fcos, fsin, DIM, DIM / 32);

    // causal flash attention
    attn_mfma<<<dim3(TSEQ / 64, NH, BATCH), 256, 0, stream>>>(qb, kb, vb, ao);

    // output projection (bf16 MFMA, fp32 out)
    gemm_mfma<0><<<dim3(NO_PAD / 128, M / 128), 256, 0, stream>>>(
        ao, woT, nullptr, nullptr, nullptr, out, nullptr, nullptr, NQ, NQ / 32);
}

// Round 6
// 313.832 us; speedup vs baseline: 13.2661x; 1.4817x over previous
//
#include <hip/hip_runtime.h>
#include <hip/hip_bf16.h>
#include <cmath>
#include <type_traits>

#define DIM  960
#define NH   15
#define NKV  5
#define HD   64
#define GQ   3
#define TSEQ 2048
#define BATCH 4
#define NQ   (NH * HD)        // 960
#define NKVD (NKV * HD)       // 320
#define NTOT (NQ + 2 * NKVD)  // 1600
#define NTOT_PAD 1664         // 13 * 128
#define NO_PAD   1024         // 8 * 128

using bf16x8 = __attribute__((ext_vector_type(8))) short;
using f32x4  = __attribute__((ext_vector_type(4))) float;

// 0.125 (1/sqrt(HD)) * log2(e): fold softmax scale + exp->exp2 into Q
#define SCALE_L2E 0.18033688011112042f

static __device__ __forceinline__ ushort f2bf(float f) {
    __hip_bfloat16 h = __float2bfloat16(f);
    return *reinterpret_cast<ushort*>(&h);
}

// v_exp_f32 is natively 2^x; avoid glibc macro collision with __exp2f
static __device__ __forceinline__ float fast_exp2(float x) {
    return __builtin_amdgcn_exp2f(x);
}

typedef const __attribute__((address_space(1))) unsigned char* gp_t;
typedef __attribute__((address_space(3))) unsigned char* lp_t;

static __device__ __forceinline__ void gload_lds16(const void* g, void* l) {
    // LDS dest = wave-uniform base + lane*16 (m104); source is per-lane.
    __builtin_amdgcn_global_load_lds((gp_t)g, (lp_t)l, 16, 0, 0);
}

// ---------------------------------------------------------------------------
// x fp32 -> bf16
// ---------------------------------------------------------------------------
__global__ __launch_bounds__(256)
void cvt_x(const float* __restrict__ x, ushort* __restrict__ xb, int n4)
{
    int i = blockIdx.x * blockDim.x + threadIdx.x;
    const int stride = gridDim.x * blockDim.x;
    for (; i < n4; i += stride) {
        float4 v = reinterpret_cast<const float4*>(x)[i];
        ushort4 o = {f2bf(v.x), f2bf(v.y), f2bf(v.z), f2bf(v.w)};
        reinterpret_cast<ushort4*>(xb)[i] = o;
    }
}

// ---------------------------------------------------------------------------
// Weight transpose + bf16 convert. src [960][ncols] fp32 -> dst[dstoff+c][k].
// ---------------------------------------------------------------------------
__global__ __launch_bounds__(256)
void transpose_wb(const float* __restrict__ wq, const float* __restrict__ wk,
                  const float* __restrict__ wv, const float* __restrict__ wo,
                  ushort* __restrict__ wqkvT, ushort* __restrict__ woT)
{
    __shared__ float tile[32][33];
    const float* src; ushort* dst; int ncols, dstoff;
    switch (blockIdx.z) {
        case 0:  src = wq; ncols = NQ;   dst = wqkvT; dstoff = 0;    break;
        case 1:  src = wk; ncols = NKVD; dst = wqkvT; dstoff = NQ;   break;
        case 2:  src = wv; ncols = NKVD; dst = wqkvT; dstoff = NQ + NKVD; break;
        default: src = wo; ncols = NQ;   dst = woT;   dstoff = 0;    break;
    }
    const int c0 = blockIdx.x * 32;
    if (c0 >= ncols) return;
    const int k0 = blockIdx.y * 32;
    const int tx = threadIdx.x & 31, ty = threadIdx.x >> 5;
    #pragma unroll
    for (int i = 0; i < 4; ++i)
        tile[ty * 4 + i][tx] = src[(size_t)(k0 + ty * 4 + i) * ncols + c0 + tx];
    __syncthreads();
    #pragma unroll
    for (int i = 0; i < 4; ++i) {
        const int c = c0 + ty * 4 + i;
        dst[(size_t)(dstoff + c) * DIM + k0 + tx] = f2bf(tile[tx][ty * 4 + i]);
    }
}

// ---------------------------------------------------------------------------
// bf16 MFMA GEMM (m97-style 128x128, BK=32, dbuf LDS via global_load_lds).
// EPI==1: QKV + RoPE epilogue. q scaled by SCALE_L2E, stored [row][NQ];
//         k stored [b][kvh][t][d]; v stored TRANSPOSED [b][kvh][d][t].
// EPI==0: fp32 C store.
// ---------------------------------------------------------------------------
template<int EPI>
__global__ __launch_bounds__(256)
void gemm_mfma(const ushort* __restrict__ A,    // [M][K] bf16
               const ushort* __restrict__ BT,   // [Npad][K] bf16
               ushort* __restrict__ Cq, ushort* __restrict__ Ck,
               ushort* __restrict__ Cv, float* __restrict__ Cf,
               const float* __restrict__ fcos, const float* __restrict__ fsin,
               int K, int NT)
{
    __shared__ char lds[32 * 1024];

    const int tid  = threadIdx.x;
    const int wave = tid >> 6;
    const int lane = tid & 63;
    const int lr   = lane & 15;
    const int lg   = lane >> 4;
    const int wr   = wave >> 1;
    const int wc   = wave & 1;
    const int row0 = blockIdx.y * 128;
    const int col0 = blockIdx.x * 128;

    const int swz = ((lr >> 1) & 3) << 4;

    f32x4 acc[4][4];
    #pragma unroll
    for (int mi = 0; mi < 4; ++mi)
        #pragma unroll
        for (int ni = 0; ni < 4; ++ni)
            acc[mi][ni] = f32x4{0.f, 0.f, 0.f, 0.f};

    const int sr  = lane >> 2;
    const int scp = lane & 3;

    auto stage = [&](int t, int bufsel) {
        const int k0 = t * 32;
        char* Ab = lds + bufsel * 16384;
        char* Bb = Ab + 8192;
        #pragma unroll
        for (int i = 0; i < 2; ++i) {
            const int r0 = (wave * 2 + i) * 16;
            const int r  = r0 + sr;
            const int gc = scp ^ ((r >> 1) & 3);
            gload_lds16(A + (size_t)(row0 + r) * K + k0 + gc * 8, Ab + r0 * 64);
        }
        #pragma unroll
        for (int i = 0; i < 2; ++i) {
            const int r0 = (wave * 2 + i) * 16;
            const int r  = r0 + sr;
            const int gc = scp ^ ((r >> 1) & 3);
            gload_lds16(BT + (size_t)(col0 + r) * K + k0 + gc * 8, Bb + r0 * 64);
        }
    };

    auto compute = [&](int bufsel) {
        char* Ab = lds + bufsel * 16384;
        char* Bb = Ab + 8192;
        bf16x8 af[4], bfr[4];
        #pragma unroll
        for (int mi = 0; mi < 4; ++mi)
            af[mi] = *reinterpret_cast<const bf16x8*>(
                Ab + (wr * 64 + mi * 16 + lr) * 64 + (lg * 16 ^ swz));
        #pragma unroll
        for (int ni = 0; ni < 4; ++ni)
            bfr[ni] = *reinterpret_cast<const bf16x8*>(
                Bb + (wc * 64 + ni * 16 + lr) * 64 + (lg * 16 ^ swz));
        #pragma unroll
        for (int mi = 0; mi < 4; ++mi)
            #pragma unroll
            for (int ni = 0; ni < 4; ++ni)
                acc[mi][ni] = __builtin_amdgcn_mfma_f32_16x16x32_bf16(
                    af[mi], bfr[ni], acc[mi][ni], 0, 0, 0);
    };

    stage(0, 0);
    __syncthreads();
    for (int t = 0; t < NT; ++t) {
        if (t + 1 < NT) stage(t + 1, (t & 1) ^ 1);
        compute(t & 1);
        __syncthreads();
    }

    // ---- epilogue ----
    #pragma unroll
    for (int mi = 0; mi < 4; ++mi) {
        #pragma unroll
        for (int q = 0; q < 4; ++q) {
            const int row = row0 + wr * 64 + mi * 16 + lg * 4 + q;
            const int t   = row & (TSEQ - 1);
            const int bb  = row >> 11;          // row / TSEQ
            #pragma unroll
            for (int ni = 0; ni < 4; ++ni) {
                const float vv = acc[mi][ni][q];
                const int col = col0 + wc * 64 + ni * 16 + lr;
                if (EPI == 0) {
                    if (col < DIM)
                        Cf[(size_t)row * DIM + col] = vv;
                } else {
                    const float pv = __shfl_xor(vv, 1);   // RoPE partner
                    if (col < NQ + NKVD) {
                        const int j = (col & (HD - 1)) >> 1;
                        const float c = fcos[t * 32 + j];
                        const float s = fsin[t * 32 + j];
                        const float ov = (lr & 1) ? (pv * s + vv * c)
                                                  : (vv * c - pv * s);
                        if (col < NQ) {
                            Cq[(size_t)row * NQ + col] = f2bf(ov * SCALE_L2E);
                        } else {
                            const int ck  = col - NQ;
                            const int kvh = ck >> 6, d = ck & 63;
                            Ck[((size_t)(bb * NKV + kvh) * TSEQ + t) * HD + d] = f2bf(ov);
                        }
                    } else if (col < NTOT) {
                        const int cv  = col - NQ - NKVD;
                        const int kvh = cv >> 6, d = cv & 63;
                        Cv[((size_t)(bb * NKV + kvh) * HD + d) * TSEQ + t] = f2bf(vv);
                    }
                }
            }
        }
    }
}

// ---------------------------------------------------------------------------
// Flash attention, bf16 MFMA. Pair-scheduled: block does Q-tiles {qa, 31-qa}
// (constant 33 K-tiles). K [b][kvh][t][d] and V^T [b][kvh][d][t] staged via
// global_load_lds w16, double-buffered, chunk-XOR swizzle pre-applied on the
// global source. Softmax in exp2 domain (Q pre-scaled by 0.125*log2e).
// LDS: K dbuf 2x8KB | V^T dbuf 2x8KB | P 4x2KB = 40 KB.
// ---------------------------------------------------------------------------
__global__ __launch_bounds__(256)
void attn_mfma(const ushort* __restrict__ qh,
               const ushort* __restrict__ kh,
               const ushort* __restrict__ vh,
               ushort* __restrict__ ao)
{
    __shared__ char lds[40960];

    const int qa  = blockIdx.x;        // 0..15
    const int h   = blockIdx.y;
    const int b   = blockIdx.z;
    const int kvh = h / GQ;
    const int tid  = threadIdx.x;
    const int wave = tid >> 6;
    const int lane = tid & 63;
    const int lr   = lane & 15;
    const int lg   = lane >> 4;

    char* Pw = lds + 32768 + wave * 2048;
    const ushort* kbase = kh + (size_t)(b * NKV + kvh) * TSEQ * HD;
    const ushort* vbase = vh + (size_t)(b * NKV + kvh) * HD * TSEQ;

    const int srow8 = lane >> 3;   // 0..7
    const int sc    = lane & 7;

    auto stageKV = [&](int kt, int bufsel) {
        const int k0s = kt * 64;
        char* Kb = lds + bufsel * 8192;
        char* Vb = lds + 16384 + bufsel * 8192;
        #pragma unroll
        for (int i = 0; i < 2; ++i) {
            const int s16 = wave * 2 + i;          // 0..7
            const int row = s16 * 8 + srow8;       // 0..63
            const int cs  = sc ^ (row & 7);
            gload_lds16(kbase + (size_t)(k0s + row) * HD + cs * 8, Kb + s16 * 1024);
            gload_lds16(vbase + (size_t)row * TSEQ + k0s + cs * 8, Vb + s16 * 1024);
        }
    };

    #pragma unroll 1
    for (int seg = 0; seg < 2; ++seg) {
        const int qt = seg ? (TSEQ / 64 - 1) - qa : qa;
        const int q0 = qt * 64;

        bf16x8 qf[2];
        {
            const ushort* qp = qh + ((size_t)(b * TSEQ + q0 + wave * 16 + lr) * NH + h) * HD;
            qf[0] = *reinterpret_cast<const bf16x8*>(qp + lg * 8);
            qf[1] = *reinterpret_cast<const bf16x8*>(qp + 32 + lg * 8);
        }

        f32x4 O[4];
        float m[4], l[4];
        #pragma unroll
        for (int dt = 0; dt < 4; ++dt) O[dt] = f32x4{0.f, 0.f, 0.f, 0.f};
        #pragma unroll
        for (int r = 0; r < 4; ++r) { m[r] = -INFINITY; l[r] = 0.f; }

        auto core = [&](auto diagc, int kt, int bufsel) {
            constexpr bool DIAG = decltype(diagc)::value;
            const int k0 = kt * 64;
            char* Kb = lds + bufsel * 8192;
            char* Vb = lds + 16384 + bufsel * 8192;

            // ---- S = Q K^T (already in exp2 domain) ----
            f32x4 s4[4];
            __builtin_amdgcn_s_setprio(1);
            #pragma unroll
            for (int c = 0; c < 4; ++c) {
                f32x4 acc = f32x4{0.f, 0.f, 0.f, 0.f};
                #pragma unroll
                for (int ks = 0; ks < 2; ++ks) {
                    const int row = c * 16 + lr;
                    const int db  = row * 128 + (((ks * 4 + lg) * 16) ^ ((row & 7) << 4));
                    bf16x8 kf = *reinterpret_cast<const bf16x8*>(Kb + db);
                    acc = __builtin_amdgcn_mfma_f32_16x16x32_bf16(qf[ks], kf, acc, 0, 0, 0);
                }
                s4[c] = acc;
            }
            __builtin_amdgcn_s_setprio(0);

            // ---- online softmax (exp2 domain) ----
            float sv[4][4], mt[4];
            #pragma unroll
            for (int reg = 0; reg < 4; ++reg) {
                const int qrow = q0 + wave * 16 + lg * 4 + reg;
                mt[reg] = -INFINITY;
                #pragma unroll
                for (int c = 0; c < 4; ++c) {
                    float x = s4[c][reg];
                    if (DIAG && (k0 + c * 16 + lr > qrow)) x = -INFINITY;
                    sv[c][reg] = x;
                    mt[reg] = fmaxf(mt[reg], x);
                }
            }
            #pragma unroll
            for (int reg = 0; reg < 4; ++reg) {
                float v = mt[reg];
                v = fmaxf(v, __shfl_xor(v, 1));
                v = fmaxf(v, __shfl_xor(v, 2));
                v = fmaxf(v, __shfl_xor(v, 4));
                v = fmaxf(v, __shfl_xor(v, 8));
                const float mn   = fmaxf(m[reg], v);
                const float corr = fast_exp2(m[reg] - mn);
                m[reg] = mn;
                float ls = 0.f;
                const int prow = lg * 4 + reg;
                #pragma unroll
                for (int c = 0; c < 4; ++c) {
                    const float p = fast_exp2(sv[c][reg] - mn);
                    ls += p;
                    const int db = (prow * 128 + (c * 16 + lr) * 2) ^ ((prow & 7) << 4);
                    *reinterpret_cast<ushort*>(Pw + db) = f2bf(p);
                }
                ls += __shfl_xor(ls, 1);
                ls += __shfl_xor(ls, 2);
                ls += __shfl_xor(ls, 4);
                ls += __shfl_xor(ls, 8);
                l[reg] = l[reg] * corr + ls;
                #pragma unroll
                for (int dt = 0; dt < 4; ++dt) O[dt][reg] *= corr;
            }

            asm volatile("s_waitcnt lgkmcnt(0)" ::: "memory");
            __builtin_amdgcn_sched_barrier(0);   // rule 18

            // ---- O += P V ----
            bf16x8 pf[2];
            #pragma unroll
            for (int ks = 0; ks < 2; ++ks) {
                const int db = (lr * 128 + ks * 64 + lg * 16) ^ ((lr & 7) << 4);
                pf[ks] = *reinterpret_cast<const bf16x8*>(Pw + db);
            }
            __builtin_amdgcn_s_setprio(1);
            #pragma unroll
            for (int dt = 0; dt < 4; ++dt) {
                #pragma unroll
                for (int ks = 0; ks < 2; ++ks) {
                    const int row = dt * 16 + lr;
                    const int db  = row * 128 + (((ks * 4 + lg) * 16) ^ ((row & 7) << 4));
                    bf16x8 vf = *reinterpret_cast<const bf16x8*>(Vb + db);
                    O[dt] = __builtin_amdgcn_mfma_f32_16x16x32_bf16(pf[ks], vf, O[dt], 0, 0, 0);
                }
            }
            __builtin_amdgcn_s_setprio(0);
        };

        stageKV(0, 0);
        __syncthreads();
        int buf = 0;
        for (int kt = 0; kt <= qt; ++kt) {
            if (kt < qt) stageKV(kt + 1, buf ^ 1);
            if (kt == qt) core(std::integral_constant<bool, true>{}, kt, buf);
            else          core(std::integral_constant<bool, false>{}, kt, buf);
            __syncthreads();
            buf ^= 1;
        }

        // ---- epilogue: O / l -> ao bf16 [row][NQ] ----
        #pragma unroll
        for (int reg = 0; reg < 4; ++reg) {
            const float inv = 1.f / l[reg];
            const int r = q0 + wave * 16 + lg * 4 + reg;
            #pragma unroll
            for (int dt = 0; dt < 4; ++dt) {
                ao[(size_t)(b * TSEQ + r) * NQ + h * HD + dt * 16 + lr] =
                    f2bf(O[dt][reg] * inv);
            }
        }
    }
}

// ---------------------------------------------------------------------------
extern "C" void kernel_launch(void* const* d_in, const int* in_sizes, int n_in,
                              void* d_out, int out_size, void* d_ws, size_t ws_size,
                              hipStream_t stream)
{
    const float* x    = (const float*)d_in[0];
    const float* fcos = (const float*)d_in[1];
    const float* fsin = (const float*)d_in[2];
    const float* wq   = (const float*)d_in[3];
    const float* wk   = (const float*)d_in[4];
    const float* wv   = (const float*)d_in[5];
    const float* wo   = (const float*)d_in[6];
    float* out = (float*)d_out;

    const int M = BATCH * TSEQ;   // 8192

    // workspace: xb | wqkvT | woT | qb | kb(KVH-major) | vt(transposed) | ao
    ushort* xb    = (ushort*)d_ws;
    ushort* wqkvT = xb    + (size_t)M * DIM;
    ushort* woT   = wqkvT + (size_t)NTOT_PAD * DIM;
    ushort* qb    = woT   + (size_t)NO_PAD * DIM;
    ushort* kb    = qb    + (size_t)M * NQ;
    ushort* vt    = kb    + (size_t)M * NKVD;
    ushort* ao    = vt    + (size_t)M * NKVD;

    cvt_x<<<2048, 256, 0, stream>>>(x, xb, M * DIM / 4);
    transpose_wb<<<dim3(30, 30, 4), 256, 0, stream>>>(wq, wk, wv, wo, wqkvT, woT);

    // QKV projection + RoPE (bf16 MFMA); writes q (scaled), k, v^T caches
    gemm_mfma<1><<<dim3(NTOT_PAD / 128, M / 128), 256, 0, stream>>>(
        xb, wqkvT, qb, kb, vt, nullptr, fcos, fsin, DIM, DIM / 32);

    // causal flash attention (pair-scheduled, dbuf gload_lds staging)
    attn_mfma<<<dim3(TSEQ / 128, NH, BATCH), 256, 0, stream>>>(qb, kb, vt, ao);

    // output projection (bf16 MFMA, fp32 out)
    gemm_mfma<0><<<dim3(NO_PAD / 128, M / 128), 256, 0, stream>>>(
        ao, woT, nullptr, nullptr, nullptr, out, nullptr, nullptr, NQ, NQ / 32);
}

// Round 7
// 250.436 us; speedup vs baseline: 16.6243x; 1.2531x over previous
//
#include <hip/hip_runtime.h>
#include <hip/hip_bf16.h>
#include <cmath>
#include <type_traits>

#define DIM  960
#define NH   15
#define NKV  5
#define HD   64
#define GQ   3
#define TSEQ 2048
#define BATCH 4
#define NQ   (NH * HD)        // 960
#define NKVD (NKV * HD)       // 320
#define NTOT (NQ + 2 * NKVD)  // 1600
#define NTOT_PAD 1664         // 13 * 128
#define NO_PAD   1024         // 8 * 128

using bf16x8 = __attribute__((ext_vector_type(8))) short;
using f32x4  = __attribute__((ext_vector_type(4))) float;
using f32x16 = __attribute__((ext_vector_type(16))) float;

// 0.125 (1/sqrt(HD)) * log2(e): fold softmax scale + exp->exp2 into Q
#define SCALE_L2E 0.18033688011112042f

static __device__ __forceinline__ ushort f2bf(float f) {
    __hip_bfloat16 h = __float2bfloat16(f);
    return *reinterpret_cast<ushort*>(&h);
}

// v_exp_f32 is natively 2^x; avoid glibc macro collision with __exp2f
static __device__ __forceinline__ float fast_exp2(float x) {
    return __builtin_amdgcn_exp2f(x);
}

typedef const __attribute__((address_space(1))) unsigned char* gp_t;
typedef __attribute__((address_space(3))) unsigned char* lp_t;

static __device__ __forceinline__ void gload_lds16(const void* g, void* l) {
    // LDS dest = wave-uniform base + lane*16 (m104); source is per-lane.
    __builtin_amdgcn_global_load_lds((gp_t)g, (lp_t)l, 16, 0, 0);
}

// V-cache column permutation: position p holds key k such that, for
// p = 16s + 8*hi + j, k = 16s + crow(j,hi) with crow(j,hi)=(j&3)+8*(j>>2)+4*hi.
// This makes the PV B-operand (P^T from registers) need NO cross-lane moves.
static __device__ __forceinline__ int vpos(int t) {
    return (t & ~15) | ((( t >> 2) & 1) << 3) | (t & 3) | (((t >> 3) & 1) << 2);
}

// ---------------------------------------------------------------------------
// x fp32 -> bf16
// ---------------------------------------------------------------------------
__global__ __launch_bounds__(256)
void cvt_x(const float* __restrict__ x, ushort* __restrict__ xb, int n4)
{
    int i = blockIdx.x * blockDim.x + threadIdx.x;
    const int stride = gridDim.x * blockDim.x;
    for (; i < n4; i += stride) {
        float4 v = reinterpret_cast<const float4*>(x)[i];
        ushort4 o = {f2bf(v.x), f2bf(v.y), f2bf(v.z), f2bf(v.w)};
        reinterpret_cast<ushort4*>(xb)[i] = o;
    }
}

// ---------------------------------------------------------------------------
// Weight transpose + bf16 convert. src [960][ncols] fp32 -> dst[dstoff+c][k].
// ---------------------------------------------------------------------------
__global__ __launch_bounds__(256)
void transpose_wb(const float* __restrict__ wq, const float* __restrict__ wk,
                  const float* __restrict__ wv, const float* __restrict__ wo,
                  ushort* __restrict__ wqkvT, ushort* __restrict__ woT)
{
    __shared__ float tile[32][33];
    const float* src; ushort* dst; int ncols, dstoff;
    switch (blockIdx.z) {
        case 0:  src = wq; ncols = NQ;   dst = wqkvT; dstoff = 0;    break;
        case 1:  src = wk; ncols = NKVD; dst = wqkvT; dstoff = NQ;   break;
        case 2:  src = wv; ncols = NKVD; dst = wqkvT; dstoff = NQ + NKVD; break;
        default: src = wo; ncols = NQ;   dst = woT;   dstoff = 0;    break;
    }
    const int c0 = blockIdx.x * 32;
    if (c0 >= ncols) return;
    const int k0 = blockIdx.y * 32;
    const int tx = threadIdx.x & 31, ty = threadIdx.x >> 5;
    #pragma unroll
    for (int i = 0; i < 4; ++i)
        tile[ty * 4 + i][tx] = src[(size_t)(k0 + ty * 4 + i) * ncols + c0 + tx];
    __syncthreads();
    #pragma unroll
    for (int i = 0; i < 4; ++i) {
        const int c = c0 + ty * 4 + i;
        dst[(size_t)(dstoff + c) * DIM + k0 + tx] = f2bf(tile[tx][ty * 4 + i]);
    }
}

// ---------------------------------------------------------------------------
// bf16 MFMA GEMM (m97-style 128x128, BK=32, dbuf LDS via global_load_lds).
// EPI==1: QKV + RoPE epilogue. q scaled by SCALE_L2E, stored [row][NQ];
//         k stored [b][kvh][t][d]; v stored TRANSPOSED+col-permuted
//         [b][kvh][d][vpos(t)].
// EPI==0: fp32 C store.
// ---------------------------------------------------------------------------
template<int EPI>
__global__ __launch_bounds__(256)
void gemm_mfma(const ushort* __restrict__ A,    // [M][K] bf16
               const ushort* __restrict__ BT,   // [Npad][K] bf16
               ushort* __restrict__ Cq, ushort* __restrict__ Ck,
               ushort* __restrict__ Cv, float* __restrict__ Cf,
               const float* __restrict__ fcos, const float* __restrict__ fsin,
               int K, int NT)
{
    __shared__ char lds[32 * 1024];

    const int tid  = threadIdx.x;
    const int wave = tid >> 6;
    const int lane = tid & 63;
    const int lr   = lane & 15;
    const int lg   = lane >> 4;
    const int wr   = wave >> 1;
    const int wc   = wave & 1;
    const int row0 = blockIdx.y * 128;
    const int col0 = blockIdx.x * 128;

    const int swz = ((lr >> 1) & 3) << 4;

    f32x4 acc[4][4];
    #pragma unroll
    for (int mi = 0; mi < 4; ++mi)
        #pragma unroll
        for (int ni = 0; ni < 4; ++ni)
            acc[mi][ni] = f32x4{0.f, 0.f, 0.f, 0.f};

    const int sr  = lane >> 2;
    const int scp = lane & 3;

    auto stage = [&](int t, int bufsel) {
        const int k0 = t * 32;
        char* Ab = lds + bufsel * 16384;
        char* Bb = Ab + 8192;
        #pragma unroll
        for (int i = 0; i < 2; ++i) {
            const int r0 = (wave * 2 + i) * 16;
            const int r  = r0 + sr;
            const int gc = scp ^ ((r >> 1) & 3);
            gload_lds16(A + (size_t)(row0 + r) * K + k0 + gc * 8, Ab + r0 * 64);
        }
        #pragma unroll
        for (int i = 0; i < 2; ++i) {
            const int r0 = (wave * 2 + i) * 16;
            const int r  = r0 + sr;
            const int gc = scp ^ ((r >> 1) & 3);
            gload_lds16(BT + (size_t)(col0 + r) * K + k0 + gc * 8, Bb + r0 * 64);
        }
    };

    auto compute = [&](int bufsel) {
        char* Ab = lds + bufsel * 16384;
        char* Bb = Ab + 8192;
        bf16x8 af[4], bfr[4];
        #pragma unroll
        for (int mi = 0; mi < 4; ++mi)
            af[mi] = *reinterpret_cast<const bf16x8*>(
                Ab + (wr * 64 + mi * 16 + lr) * 64 + (lg * 16 ^ swz));
        #pragma unroll
        for (int ni = 0; ni < 4; ++ni)
            bfr[ni] = *reinterpret_cast<const bf16x8*>(
                Bb + (wc * 64 + ni * 16 + lr) * 64 + (lg * 16 ^ swz));
        #pragma unroll
        for (int mi = 0; mi < 4; ++mi)
            #pragma unroll
            for (int ni = 0; ni < 4; ++ni)
                acc[mi][ni] = __builtin_amdgcn_mfma_f32_16x16x32_bf16(
                    af[mi], bfr[ni], acc[mi][ni], 0, 0, 0);
    };

    stage(0, 0);
    __syncthreads();
    for (int t = 0; t < NT; ++t) {
        if (t + 1 < NT) stage(t + 1, (t & 1) ^ 1);
        compute(t & 1);
        __syncthreads();
    }

    // ---- epilogue ----
    #pragma unroll
    for (int mi = 0; mi < 4; ++mi) {
        #pragma unroll
        for (int q = 0; q < 4; ++q) {
            const int row = row0 + wr * 64 + mi * 16 + lg * 4 + q;
            const int t   = row & (TSEQ - 1);
            const int bb  = row >> 11;          // row / TSEQ
            #pragma unroll
            for (int ni = 0; ni < 4; ++ni) {
                const float vv = acc[mi][ni][q];
                const int col = col0 + wc * 64 + ni * 16 + lr;
                if (EPI == 0) {
                    if (col < DIM)
                        Cf[(size_t)row * DIM + col] = vv;
                } else {
                    const float pv = __shfl_xor(vv, 1);   // RoPE partner
                    if (col < NQ + NKVD) {
                        const int j = (col & (HD - 1)) >> 1;
                        const float c = fcos[t * 32 + j];
                        const float s = fsin[t * 32 + j];
                        const float ov = (lr & 1) ? (pv * s + vv * c)
                                                  : (vv * c - pv * s);
                        if (col < NQ) {
                            Cq[(size_t)row * NQ + col] = f2bf(ov * SCALE_L2E);
                        } else {
                            const int ck  = col - NQ;
                            const int kvh = ck >> 6, d = ck & 63;
                            Ck[((size_t)(bb * NKV + kvh) * TSEQ + t) * HD + d] = f2bf(ov);
                        }
                    } else if (col < NTOT) {
                        const int cv  = col - NQ - NKVD;
                        const int kvh = cv >> 6, d = cv & 63;
                        Cv[((size_t)(bb * NKV + kvh) * HD + d) * TSEQ + vpos(t)] = f2bf(vv);
                    }
                }
            }
        }
    }
}

// ---------------------------------------------------------------------------
// Flash attention, swapped-operand 32x32x16 MFMA, fully lane-local softmax.
// Block = 4 waves x 32 Q-rows = 128 Q-rows; pair-scheduled {qa, 15-qa}
// (constant 34 K-tiles). KVBLK = 64.
//  S^T = mfma(K, Q): lane owns P[qrow = lane&31] for 64 keys (2 f32x16).
//  O^T = mfma(V^T, P^T): lane owns O[qrow = lane&31], d spread over regs.
//  P packs from registers into the B-operand with zero cross-lane moves
//  (V cache columns pre-permuted by vpos in the GEMM epilogue).
// LDS: K dbuf 2x8KB | V^T dbuf 2x8KB = 32 KB. XOR swizzle (row&7)<<4.
// ---------------------------------------------------------------------------
__global__ __launch_bounds__(256)
void attn_mfma(const ushort* __restrict__ qh,
               const ushort* __restrict__ kh,
               const ushort* __restrict__ vh,
               ushort* __restrict__ ao)
{
    __shared__ char lds[32768];

    const int qa  = blockIdx.x;        // 0..7
    const int h   = blockIdx.y;
    const int b   = blockIdx.z;
    const int kvh = h / GQ;
    const int tid  = threadIdx.x;
    const int wave = tid >> 6;
    const int lane = tid & 63;
    const int ln31 = lane & 31;
    const int hi   = lane >> 5;        // k-half of A/B fragments
    const int hi4  = hi * 4;
    const int woff = wave * 32;

    const ushort* kbase = kh + (size_t)(b * NKV + kvh) * TSEQ * HD;
    const ushort* vbase = vh + (size_t)(b * NKV + kvh) * HD * TSEQ;

    const int srow8 = lane >> 3;   // 0..7
    const int sc    = lane & 7;

    auto stageKV = [&](int kt, int bufsel) {
        const int k0s = kt * 64;
        char* Kb = lds + bufsel * 8192;
        char* Vb = lds + 16384 + bufsel * 8192;
        #pragma unroll
        for (int i = 0; i < 2; ++i) {
            const int s16 = wave * 2 + i;          // 0..7
            const int row = s16 * 8 + srow8;       // 0..63
            const int cs  = sc ^ (row & 7);
            gload_lds16(kbase + (size_t)(k0s + row) * HD + cs * 8, Kb + s16 * 1024);
            gload_lds16(vbase + (size_t)row * TSEQ + k0s + cs * 8, Vb + s16 * 1024);
        }
    };

    #pragma unroll 1
    for (int seg = 0; seg < 2; ++seg) {
        const int qt   = seg ? 15 - qa : qa;
        const int q0   = qt * 128;
        const int qrow = q0 + woff + ln31;     // this lane's Q row (global)

        // Q fragments: B-operand of swapped QK^T. Slice s: d = s*16 + hi*8.
        bf16x8 qf[4];
        {
            const ushort* qp = qh + ((size_t)(b * TSEQ) + qrow) * NQ + h * HD + hi * 8;
            #pragma unroll
            for (int s = 0; s < 4; ++s)
                qf[s] = *reinterpret_cast<const bf16x8*>(qp + s * 16);
        }

        f32x16 O0 = {}, O1 = {};
        float m = -INFINITY, l = 0.f;

        const int nkt = 2 * qt + 2;

        auto core = [&](auto diagc, int kt, int bufsel) {
            constexpr bool DIAG = decltype(diagc)::value;
            const int k0 = kt * 64;
            char* Kb = lds + bufsel * 8192;
            char* Vb = lds + 16384 + bufsel * 8192;

            if (DIAG && k0 > q0 + woff + 31) return;   // wave fully masked

            // ---- S^T = K  Q^T : per key-half one 32x32 tile, 4 d-slices ----
            f32x16 acc0 = {}, acc1 = {};
            __builtin_amdgcn_s_setprio(1);
            #pragma unroll
            for (int s = 0; s < 4; ++s) {
                const int db0 = ln31 * 128 + (((s * 2 + hi) * 16) ^ ((ln31 & 7) << 4));
                bf16x8 kf0 = *reinterpret_cast<const bf16x8*>(Kb + db0);
                acc0 = __builtin_amdgcn_mfma_f32_32x32x16_bf16(kf0, qf[s], acc0, 0, 0, 0);
                bf16x8 kf1 = *reinterpret_cast<const bf16x8*>(Kb + 4096 + db0);
                acc1 = __builtin_amdgcn_mfma_f32_32x32x16_bf16(kf1, qf[s], acc1, 0, 0, 0);
            }
            __builtin_amdgcn_s_setprio(0);

            // ---- lane-local online softmax (exp2 domain) ----
            // lane holds S[qrow][key = k0 + 32*h2 + (r&3)+8*(r>>2)+hi4]
            if (DIAG) {
                #pragma unroll
                for (int r = 0; r < 16; ++r) {
                    const int kc = k0 + ((r & 3) + 8 * (r >> 2)) + hi4;
                    if (kc > qrow)      acc0[r] = -INFINITY;
                    if (kc + 32 > qrow) acc1[r] = -INFINITY;
                }
            }
            float mt = -INFINITY;
            #pragma unroll
            for (int r = 0; r < 16; ++r) {
                mt = fmaxf(mt, acc0[r]);
                mt = fmaxf(mt, acc1[r]);
            }
            mt = fmaxf(mt, __shfl_xor(mt, 32));
            const float mn   = fmaxf(m, mt);
            const float corr = fast_exp2(m - mn);
            m = mn;

            float ls0 = 0.f, ls1 = 0.f;
            #pragma unroll
            for (int r = 0; r < 16; ++r) {
                const float p0 = fast_exp2(acc0[r] - mn);
                const float p1 = fast_exp2(acc1[r] - mn);
                acc0[r] = p0; acc1[r] = p1;
                ls0 += p0; ls1 += p1;
            }
            float ls = ls0 + ls1;
            ls += __shfl_xor(ls, 32);
            l = l * corr + ls;
            O0 = O0 * corr;
            O1 = O1 * corr;

            // ---- pack P to bf16 fragments (pure in-lane) ----
            // slice ss: pa[ss][j] = P at key 16*ss + crow(j,hi) = reg 8*(ss&1)+j
            // of half ss>>1 — matches V^T's vpos-permuted column order.
            bf16x8 pa[4];
            #pragma unroll
            for (int ss = 0; ss < 4; ++ss) {
                #pragma unroll
                for (int j = 0; j < 8; ++j) {
                    const int r = 8 * (ss & 1) + j;
                    const float p = (ss < 2) ? acc0[r] : acc1[r];
                    pa[ss][j] = (short)f2bf(p);
                }
            }

            // ---- O^T += V^T  P^T ----
            __builtin_amdgcn_s_setprio(1);
            #pragma unroll
            for (int ss = 0; ss < 4; ++ss) {
                const int db0 = ln31 * 128 + (((ss * 2 + hi) * 16) ^ ((ln31 & 7) << 4));
                bf16x8 vf0 = *reinterpret_cast<const bf16x8*>(Vb + db0);
                O0 = __builtin_amdgcn_mfma_f32_32x32x16_bf16(vf0, pa[ss], O0, 0, 0, 0);
                bf16x8 vf1 = *reinterpret_cast<const bf16x8*>(Vb + 4096 + db0);
                O1 = __builtin_amdgcn_mfma_f32_32x32x16_bf16(vf1, pa[ss], O1, 0, 0, 0);
            }
            __builtin_amdgcn_s_setprio(0);
        };

        stageKV(0, 0);
        __syncthreads();
        int buf = 0;
        #pragma unroll 1
        for (int kt = 0; kt < nkt; ++kt) {
            if (kt + 1 < nkt) stageKV(kt + 1, buf ^ 1);
            if (kt >= nkt - 2) core(std::integral_constant<bool, true>{}, kt, buf);
            else               core(std::integral_constant<bool, false>{}, kt, buf);
            __syncthreads();
            buf ^= 1;
        }

        // ---- epilogue: O[qrow][d = crow(r,hi) + 32*dt] / l ----
        const float inv = 1.f / l;
        ushort* aop = ao + ((size_t)(b * TSEQ) + qrow) * NQ + h * HD;
        #pragma unroll
        for (int g = 0; g < 4; ++g) {
            const int r0 = 4 * g;
            {
                const int dd = 8 * g + hi4;
                ushort4 st = {f2bf(O0[r0] * inv), f2bf(O0[r0 + 1] * inv),
                              f2bf(O0[r0 + 2] * inv), f2bf(O0[r0 + 3] * inv)};
                *reinterpret_cast<ushort4*>(aop + dd) = st;
            }
            {
                const int dd = 32 + 8 * g + hi4;
                ushort4 st = {f2bf(O1[r0] * inv), f2bf(O1[r0 + 1] * inv),
                              f2bf(O1[r0 + 2] * inv), f2bf(O1[r0 + 3] * inv)};
                *reinterpret_cast<ushort4*>(aop + dd) = st;
            }
        }
    }
}

// ---------------------------------------------------------------------------
extern "C" void kernel_launch(void* const* d_in, const int* in_sizes, int n_in,
                              void* d_out, int out_size, void* d_ws, size_t ws_size,
                              hipStream_t stream)
{
    const float* x    = (const float*)d_in[0];
    const float* fcos = (const float*)d_in[1];
    const float* fsin = (const float*)d_in[2];
    const float* wq   = (const float*)d_in[3];
    const float* wk   = (const float*)d_in[4];
    const float* wv   = (const float*)d_in[5];
    const float* wo   = (const float*)d_in[6];
    float* out = (float*)d_out;

    const int M = BATCH * TSEQ;   // 8192

    // workspace: xb | wqkvT | woT | qb | kb(KVH-major) | vt(transposed) | ao
    ushort* xb    = (ushort*)d_ws;
    ushort* wqkvT = xb    + (size_t)M * DIM;
    ushort* woT   = wqkvT + (size_t)NTOT_PAD * DIM;
    ushort* qb    = woT   + (size_t)NO_PAD * DIM;
    ushort* kb    = qb    + (size_t)M * NQ;
    ushort* vt    = kb    + (size_t)M * NKVD;
    ushort* ao    = vt    + (size_t)M * NKVD;

    cvt_x<<<2048, 256, 0, stream>>>(x, xb, M * DIM / 4);
    transpose_wb<<<dim3(30, 30, 4), 256, 0, stream>>>(wq, wk, wv, wo, wqkvT, woT);

    // QKV projection + RoPE (bf16 MFMA); writes q (scaled), k, v^T caches
    gemm_mfma<1><<<dim3(NTOT_PAD / 128, M / 128), 256, 0, stream>>>(
        xb, wqkvT, qb, kb, vt, nullptr, fcos, fsin, DIM, DIM / 32);

    // causal flash attention (swapped-operand 32x32 MFMA, lane-local softmax)
    attn_mfma<<<dim3(8, NH, BATCH), 256, 0, stream>>>(qb, kb, vt, ao);

    // output projection (bf16 MFMA, fp32 out)
    gemm_mfma<0><<<dim3(NO_PAD / 128, M / 128), 256, 0, stream>>>(
        ao, woT, nullptr, nullptr, nullptr, out, nullptr, nullptr, NQ, NQ / 32);
}

// Round 9
// 242.230 us; speedup vs baseline: 17.1874x; 1.0339x over previous
//
#include <hip/hip_runtime.h>
#include <hip/hip_bf16.h>
#include <cmath>
#include <type_traits>

#define DIM  960
#define NH   15
#define NKV  5
#define HD   64
#define GQ   3
#define TSEQ 2048
#define BATCH 4
#define NQ   (NH * HD)        // 960
#define NKVD (NKV * HD)       // 320
#define NTOT (NQ + 2 * NKVD)  // 1600
#define NTOT_PAD 1792         // 7 * 256
#define NO_PAD   1024         // 8 * 128

using bf16x8 = __attribute__((ext_vector_type(8))) short;
using f32x4  = __attribute__((ext_vector_type(4))) float;
using f32x16 = __attribute__((ext_vector_type(16))) float;

// 0.125 (1/sqrt(HD)) * log2(e): fold softmax scale + exp->exp2 into Q
#define SCALE_L2E 0.18033688011112042f

static __device__ __forceinline__ ushort f2bf(float f) {
    __hip_bfloat16 h = __float2bfloat16(f);
    return *reinterpret_cast<ushort*>(&h);
}

// v_exp_f32 is natively 2^x; avoid glibc macro collision with __exp2f
static __device__ __forceinline__ float fast_exp2(float x) {
    return __builtin_amdgcn_exp2f(x);
}

typedef const __attribute__((address_space(1))) unsigned char* gp_t;
typedef __attribute__((address_space(3))) unsigned char* lp_t;

static __device__ __forceinline__ void gload_lds16(const void* g, void* l) {
    // LDS dest = wave-uniform base + lane*16 (m104); source is per-lane.
    __builtin_amdgcn_global_load_lds((gp_t)g, (lp_t)l, 16, 0, 0);
}

// V-cache column permutation: position p holds key k such that, for
// p = 16s + 8*hi + j, k = 16s + crow(j,hi) with crow(j,hi)=(j&3)+8*(j>>2)+4*hi.
static __device__ __forceinline__ int vpos(int t) {
    return (t & ~15) | ((( t >> 2) & 1) << 3) | (t & 3) | (((t >> 3) & 1) << 2);
}

// ---------------------------------------------------------------------------
// x fp32 -> bf16
// ---------------------------------------------------------------------------
__global__ __launch_bounds__(256)
void cvt_x(const float* __restrict__ x, ushort* __restrict__ xb, int n4)
{
    int i = blockIdx.x * blockDim.x + threadIdx.x;
    const int stride = gridDim.x * blockDim.x;
    for (; i < n4; i += stride) {
        float4 v = reinterpret_cast<const float4*>(x)[i];
        ushort4 o = {f2bf(v.x), f2bf(v.y), f2bf(v.z), f2bf(v.w)};
        reinterpret_cast<ushort4*>(xb)[i] = o;
    }
}

// ---------------------------------------------------------------------------
// Weight transpose + bf16 convert. src [960][ncols] fp32 -> dst[dstoff+c][k].
// ---------------------------------------------------------------------------
__global__ __launch_bounds__(256)
void transpose_wb(const float* __restrict__ wq, const float* __restrict__ wk,
                  const float* __restrict__ wv, const float* __restrict__ wo,
                  ushort* __restrict__ wqkvT, ushort* __restrict__ woT)
{
    __shared__ float tile[32][33];
    const float* src; ushort* dst; int ncols, dstoff;
    switch (blockIdx.z) {
        case 0:  src = wq; ncols = NQ;   dst = wqkvT; dstoff = 0;    break;
        case 1:  src = wk; ncols = NKVD; dst = wqkvT; dstoff = NQ;   break;
        case 2:  src = wv; ncols = NKVD; dst = wqkvT; dstoff = NQ + NKVD; break;
        default: src = wo; ncols = NQ;   dst = woT;   dstoff = 0;    break;
    }
    const int c0 = blockIdx.x * 32;
    if (c0 >= ncols) return;
    const int k0 = blockIdx.y * 32;
    const int tx = threadIdx.x & 31, ty = threadIdx.x >> 5;
    #pragma unroll
    for (int i = 0; i < 4; ++i)
        tile[ty * 4 + i][tx] = src[(size_t)(k0 + ty * 4 + i) * ncols + c0 + tx];
    __syncthreads();
    #pragma unroll
    for (int i = 0; i < 4; ++i) {
        const int c = c0 + ty * 4 + i;
        dst[(size_t)(dstoff + c) * DIM + k0 + tx] = f2bf(tile[tx][ty * 4 + i]);
    }
}

// ---------------------------------------------------------------------------
// Deep-pipelined bf16 MFMA GEMM (T3+T4+T5+T1): 256xBN tile, BK=32, 8 waves
// (2M x 4N), double-buffered LDS, counted vmcnt (never 0 in loop), 4-phase
// K-step, setprio around MFMA clusters, XCD-swizzled 1D grid.
// K = 960 (both GEMMs). EPI==1: QKV + RoPE epilogue (q scaled by SCALE_L2E,
// k -> [b][kvh][t][d], v -> transposed+vpos-permuted [b][kvh][d][vpos(t)]).
// EPI==0: fp32 C store ([8192][960]).
// ---------------------------------------------------------------------------
template<int EPI, int BN>
__global__ __launch_bounds__(512)
void gemm_pipe(const ushort* __restrict__ A,    // [M][960] bf16
               const ushort* __restrict__ BT,   // [Npad][960] bf16
               ushort* __restrict__ Cq, ushort* __restrict__ Ck,
               ushort* __restrict__ Cv, float* __restrict__ Cf,
               const float* __restrict__ fcos, const float* __restrict__ fsin,
               int nbx)
{
    constexpr int KD  = 960;
    constexpr int BK  = 32;
    constexpr int NT  = 30;            // 960 / 32
    constexpr int PWN = BN / 4;        // per-wave N span: 64 / 32
    constexpr int NF  = PWN / 32;      // B frags per qn: 2 / 1
    constexpr int ASZ = 256 * BK * 2;  // 16384
    constexpr int BSZ = BN * BK * 2;   // 16384 / 8192
    constexpr int BUF = ASZ + BSZ;
    constexpr int AR  = ASZ / 8192;    // A stage rounds = 2
    constexpr int BR  = BSZ / 8192;    // 2 / 1
    constexpr int LPT = AR + BR;       // loads/thread/K-tile = 4 / 3

    __shared__ char lds[2 * BUF];

    const int tid  = threadIdx.x;
    const int wave = tid >> 6;
    const int lane = tid & 63;
    const int lr   = lane & 15;
    const int lg   = lane >> 4;
    const int wm   = wave >> 2;        // 0..1
    const int wn   = wave & 3;         // 0..3

    // XCD-aware block swizzle (grid % 8 == 0 for both instantiations)
    const int nwg = gridDim.x;
    const int bid = blockIdx.x;
    const int sb  = (bid & 7) * (nwg >> 3) + (bid >> 3);
    const int bx  = sb % nbx;
    const int by  = sb / nbx;
    const int row0 = by * 256;
    const int col0 = bx * BN;

    f32x4 acc[2][2][4][NF];
    #pragma unroll
    for (int qm = 0; qm < 2; ++qm)
        #pragma unroll
        for (int qn = 0; qn < 2; ++qn)
            #pragma unroll
            for (int mi = 0; mi < 4; ++mi)
                #pragma unroll
                for (int ni = 0; ni < NF; ++ni)
                    acc[qm][qn][mi][ni] = f32x4{0.f, 0.f, 0.f, 0.f};

    // staging: round rd covers 128 rows; lane -> row = +wave*16 + (lane>>2),
    // chunk = lane&3; inverse chunk-swizzle applied to GLOBAL source (rule 21)
    auto stageA = [&](int t, int bsel) {
        const int k0 = t * BK;
        #pragma unroll
        for (int rd = 0; rd < AR; ++rd) {
            const int row = rd * 128 + wave * 16 + (lane >> 2);
            const int gc  = (lane & 3) ^ ((row >> 1) & 3);
            gload_lds16(A + (size_t)(row0 + row) * KD + k0 + gc * 8,
                        lds + bsel * BUF + rd * 8192 + wave * 1024);
        }
    };
    auto stageB = [&](int t, int bsel) {
        const int k0 = t * BK;
        #pragma unroll
        for (int rd = 0; rd < BR; ++rd) {
            const int row = rd * 128 + wave * 16 + (lane >> 2);
            const int gc  = (lane & 3) ^ ((row >> 1) & 3);
            gload_lds16(BT + (size_t)(col0 + row) * KD + k0 + gc * 8,
                        lds + bsel * BUF + ASZ + rd * 8192 + wave * 1024);
        }
    };

    // frag reads (chunk-XOR swizzle, 2-way bank aliasing = free)
    auto rdA = [&](int bsel, int qm, int mi) -> bf16x8 {
        const int row = wm * 128 + qm * 64 + mi * 16 + lr;
        const int ch  = lg ^ ((row >> 1) & 3);
        return *reinterpret_cast<const bf16x8*>(lds + bsel * BUF + row * 64 + ch * 16);
    };
    auto rdB = [&](int bsel, int qn, int ni) -> bf16x8 {
        const int row = wn * PWN + qn * (PWN / 2) + ni * 16 + lr;
        const int ch  = lg ^ ((row >> 1) & 3);
        return *reinterpret_cast<const bf16x8*>(lds + bsel * BUF + ASZ + row * 64 + ch * 16);
    };

    // prologue: 2 tiles in flight
    stageA(0, 0); stageB(0, 0);
    stageA(1, 1); stageB(1, 1);

    #pragma unroll 1
    for (int t = 0; t < NT; ++t) {
        const int bsel = t & 1;
        // tile t ready: keep next tile's loads in flight (counted vmcnt)
        if (t + 1 < NT) asm volatile("s_waitcnt vmcnt(%0)" :: "i"(LPT) : "memory");
        else            asm volatile("s_waitcnt vmcnt(0)" ::: "memory");
        __builtin_amdgcn_s_barrier();
        __builtin_amdgcn_sched_barrier(0);

        // ---- ph0: read B(all)+A(qm0); MFMA (0,0) ----
        bf16x8 bfr[2][NF];
        #pragma unroll
        for (int qn = 0; qn < 2; ++qn)
            #pragma unroll
            for (int ni = 0; ni < NF; ++ni)
                bfr[qn][ni] = rdB(bsel, qn, ni);
        bf16x8 af[4];
        #pragma unroll
        for (int mi = 0; mi < 4; ++mi) af[mi] = rdA(bsel, 0, mi);
        asm volatile("s_waitcnt lgkmcnt(0)" ::: "memory");
        __builtin_amdgcn_sched_barrier(0);
        __builtin_amdgcn_s_setprio(1);
        #pragma unroll
        for (int mi = 0; mi < 4; ++mi)
            #pragma unroll
            for (int ni = 0; ni < NF; ++ni)
                acc[0][0][mi][ni] = __builtin_amdgcn_mfma_f32_16x16x32_bf16(
                    af[mi], bfr[0][ni], acc[0][0][mi][ni], 0, 0, 0);
        __builtin_amdgcn_s_setprio(0);
        __builtin_amdgcn_s_barrier();

        // ---- ph1: read A(qm1); MFMA (0,1) ----
        bf16x8 an[4];
        #pragma unroll
        for (int mi = 0; mi < 4; ++mi) an[mi] = rdA(bsel, 1, mi);
        asm volatile("s_waitcnt lgkmcnt(0)" ::: "memory");
        __builtin_amdgcn_sched_barrier(0);
        __builtin_amdgcn_s_setprio(1);
        #pragma unroll
        for (int mi = 0; mi < 4; ++mi)
            #pragma unroll
            for (int ni = 0; ni < NF; ++ni)
                acc[0][1][mi][ni] = __builtin_amdgcn_mfma_f32_16x16x32_bf16(
                    af[mi], bfr[1][ni], acc[0][1][mi][ni], 0, 0, 0);
        __builtin_amdgcn_s_setprio(0);
        __builtin_amdgcn_s_barrier();   // all LDS reads of bsel retired

        // ---- ph2: stage t+2 into freed buffer; MFMA (1,0) ----
        if (t + 2 < NT) { stageA(t + 2, bsel); stageB(t + 2, bsel); }
        __builtin_amdgcn_s_setprio(1);
        #pragma unroll
        for (int mi = 0; mi < 4; ++mi)
            #pragma unroll
            for (int ni = 0; ni < NF; ++ni)
                acc[1][0][mi][ni] = __builtin_amdgcn_mfma_f32_16x16x32_bf16(
                    an[mi], bfr[0][ni], acc[1][0][mi][ni], 0, 0, 0);
        __builtin_amdgcn_s_setprio(0);
        __builtin_amdgcn_s_barrier();

        // ---- ph3: MFMA (1,1) ----
        __builtin_amdgcn_s_setprio(1);
        #pragma unroll
        for (int mi = 0; mi < 4; ++mi)
            #pragma unroll
            for (int ni = 0; ni < NF; ++ni)
                acc[1][1][mi][ni] = __builtin_amdgcn_mfma_f32_16x16x32_bf16(
                    an[mi], bfr[1][ni], acc[1][1][mi][ni], 0, 0, 0);
        __builtin_amdgcn_s_setprio(0);
    }

    // ---- epilogue ----
    #pragma unroll
    for (int qm = 0; qm < 2; ++qm) {
        #pragma unroll
        for (int qn = 0; qn < 2; ++qn) {
            #pragma unroll
            for (int mi = 0; mi < 4; ++mi) {
                #pragma unroll
                for (int ni = 0; ni < NF; ++ni) {
                    #pragma unroll
                    for (int q = 0; q < 4; ++q) {
                        const int row = row0 + wm * 128 + qm * 64 + mi * 16 + lg * 4 + q;
                        const int col = col0 + wn * PWN + qn * (PWN / 2) + ni * 16 + lr;
                        const int t   = row & (TSEQ - 1);
                        const int bb  = row >> 11;
                        const float vv = acc[qm][qn][mi][ni][q];
                        if (EPI == 0) {
                            if (col < DIM)
                                Cf[(size_t)row * DIM + col] = vv;
                        } else {
                            const float pv = __shfl_xor(vv, 1);   // RoPE partner
                            if (col < NQ + NKVD) {
                                const int j = (col & (HD - 1)) >> 1;
                                const float c = fcos[t * 32 + j];
                                const float s = fsin[t * 32 + j];
                                const float ov = (lr & 1) ? (pv * s + vv * c)
                                                          : (vv * c - pv * s);
                                if (col < NQ) {
                                    Cq[(size_t)row * NQ + col] = f2bf(ov * SCALE_L2E);
                                } else {
                                    const int ck  = col - NQ;
                                    const int kvh = ck >> 6, d = ck & 63;
                                    Ck[((size_t)(bb * NKV + kvh) * TSEQ + t) * HD + d] = f2bf(ov);
                                }
                            } else if (col < NTOT) {
                                const int cv  = col - NQ - NKVD;
                                const int kvh = cv >> 6, d = cv & 63;
                                Cv[((size_t)(bb * NKV + kvh) * HD + d) * TSEQ + vpos(t)] = f2bf(vv);
                            }
                        }
                    }
                }
            }
        }
    }
}

// ---------------------------------------------------------------------------
// Flash attention, swapped-operand 32x32x16 MFMA, fully lane-local softmax.
// (unchanged from round 7)
// ---------------------------------------------------------------------------
__global__ __launch_bounds__(256)
void attn_mfma(const ushort* __restrict__ qh,
               const ushort* __restrict__ kh,
               const ushort* __restrict__ vh,
               ushort* __restrict__ ao)
{
    __shared__ char lds[32768];

    const int qa  = blockIdx.x;        // 0..7
    const int h   = blockIdx.y;
    const int b   = blockIdx.z;
    const int kvh = h / GQ;
    const int tid  = threadIdx.x;
    const int wave = tid >> 6;
    const int lane = tid & 63;
    const int ln31 = lane & 31;
    const int hi   = lane >> 5;        // k-half of A/B fragments
    const int hi4  = hi * 4;
    const int woff = wave * 32;

    const ushort* kbase = kh + (size_t)(b * NKV + kvh) * TSEQ * HD;
    const ushort* vbase = vh + (size_t)(b * NKV + kvh) * HD * TSEQ;

    const int srow8 = lane >> 3;   // 0..7
    const int sc    = lane & 7;

    auto stageKV = [&](int kt, int bufsel) {
        const int k0s = kt * 64;
        char* Kb = lds + bufsel * 8192;
        char* Vb = lds + 16384 + bufsel * 8192;
        #pragma unroll
        for (int i = 0; i < 2; ++i) {
            const int s16 = wave * 2 + i;          // 0..7
            const int row = s16 * 8 + srow8;       // 0..63
            const int cs  = sc ^ (row & 7);
            gload_lds16(kbase + (size_t)(k0s + row) * HD + cs * 8, Kb + s16 * 1024);
            gload_lds16(vbase + (size_t)row * TSEQ + k0s + cs * 8, Vb + s16 * 1024);
        }
    };

    #pragma unroll 1
    for (int seg = 0; seg < 2; ++seg) {
        const int qt   = seg ? 15 - qa : qa;
        const int q0   = qt * 128;
        const int qrow = q0 + woff + ln31;     // this lane's Q row (global)

        // Q fragments: B-operand of swapped QK^T. Slice s: d = s*16 + hi*8.
        bf16x8 qf[4];
        {
            const ushort* qp = qh + ((size_t)(b * TSEQ) + qrow) * NQ + h * HD + hi * 8;
            #pragma unroll
            for (int s = 0; s < 4; ++s)
                qf[s] = *reinterpret_cast<const bf16x8*>(qp + s * 16);
        }

        f32x16 O0 = {}, O1 = {};
        float m = -INFINITY, l = 0.f;

        const int nkt = 2 * qt + 2;

        auto core = [&](auto diagc, int kt, int bufsel) {
            constexpr bool DIAG = decltype(diagc)::value;
            const int k0 = kt * 64;
            char* Kb = lds + bufsel * 8192;
            char* Vb = lds + 16384 + bufsel * 8192;

            if (DIAG && k0 > q0 + woff + 31) return;   // wave fully masked

            // ---- S^T = K  Q^T : per key-half one 32x32 tile, 4 d-slices ----
            f32x16 acc0 = {}, acc1 = {};
            __builtin_amdgcn_s_setprio(1);
            #pragma unroll
            for (int s = 0; s < 4; ++s) {
                const int db0 = ln31 * 128 + (((s * 2 + hi) * 16) ^ ((ln31 & 7) << 4));
                bf16x8 kf0 = *reinterpret_cast<const bf16x8*>(Kb + db0);
                acc0 = __builtin_amdgcn_mfma_f32_32x32x16_bf16(kf0, qf[s], acc0, 0, 0, 0);
                bf16x8 kf1 = *reinterpret_cast<const bf16x8*>(Kb + 4096 + db0);
                acc1 = __builtin_amdgcn_mfma_f32_32x32x16_bf16(kf1, qf[s], acc1, 0, 0, 0);
            }
            __builtin_amdgcn_s_setprio(0);

            // ---- lane-local online softmax (exp2 domain) ----
            if (DIAG) {
                #pragma unroll
                for (int r = 0; r < 16; ++r) {
                    const int kc = k0 + ((r & 3) + 8 * (r >> 2)) + hi4;
                    if (kc > qrow)      acc0[r] = -INFINITY;
                    if (kc + 32 > qrow) acc1[r] = -INFINITY;
                }
            }
            float mt = -INFINITY;
            #pragma unroll
            for (int r = 0; r < 16; ++r) {
                mt = fmaxf(mt, acc0[r]);
                mt = fmaxf(mt, acc1[r]);
            }
            mt = fmaxf(mt, __shfl_xor(mt, 32));
            const float mn   = fmaxf(m, mt);
            const float corr = fast_exp2(m - mn);
            m = mn;

            float ls0 = 0.f, ls1 = 0.f;
            #pragma unroll
            for (int r = 0; r < 16; ++r) {
                const float p0 = fast_exp2(acc0[r] - mn);
                const float p1 = fast_exp2(acc1[r] - mn);
                acc0[r] = p0; acc1[r] = p1;
                ls0 += p0; ls1 += p1;
            }
            float ls = ls0 + ls1;
            ls += __shfl_xor(ls, 32);
            l = l * corr + ls;
            O0 = O0 * corr;
            O1 = O1 * corr;

            // ---- pack P to bf16 fragments (pure in-lane) ----
            bf16x8 pa[4];
            #pragma unroll
            for (int ss = 0; ss < 4; ++ss) {
                #pragma unroll
                for (int j = 0; j < 8; ++j) {
                    const int r = 8 * (ss & 1) + j;
                    const float p = (ss < 2) ? acc0[r] : acc1[r];
                    pa[ss][j] = (short)f2bf(p);
                }
            }

            // ---- O^T += V^T  P^T ----
            __builtin_amdgcn_s_setprio(1);
            #pragma unroll
            for (int ss = 0; ss < 4; ++ss) {
                const int db0 = ln31 * 128 + (((ss * 2 + hi) * 16) ^ ((ln31 & 7) << 4));
                bf16x8 vf0 = *reinterpret_cast<const bf16x8*>(Vb + db0);
                O0 = __builtin_amdgcn_mfma_f32_32x32x16_bf16(vf0, pa[ss], O0, 0, 0, 0);
                bf16x8 vf1 = *reinterpret_cast<const bf16x8*>(Vb + 4096 + db0);
                O1 = __builtin_amdgcn_mfma_f32_32x32x16_bf16(vf1, pa[ss], O1, 0, 0, 0);
            }
            __builtin_amdgcn_s_setprio(0);
        };

        stageKV(0, 0);
        __syncthreads();
        int buf = 0;
        #pragma unroll 1
        for (int kt = 0; kt < nkt; ++kt) {
            if (kt + 1 < nkt) stageKV(kt + 1, buf ^ 1);
            if (kt >= nkt - 2) core(std::integral_constant<bool, true>{}, kt, buf);
            else               core(std::integral_constant<bool, false>{}, kt, buf);
            __syncthreads();
            buf ^= 1;
        }

        // ---- epilogue: O[qrow][d = crow(r,hi) + 32*dt] / l ----
        const float inv = 1.f / l;
        ushort* aop = ao + ((size_t)(b * TSEQ) + qrow) * NQ + h * HD;
        #pragma unroll
        for (int g = 0; g < 4; ++g) {
            const int r0 = 4 * g;
            {
                const int dd = 8 * g + hi4;
                ushort4 st = {f2bf(O0[r0] * inv), f2bf(O0[r0 + 1] * inv),
                              f2bf(O0[r0 + 2] * inv), f2bf(O0[r0 + 3] * inv)};
                *reinterpret_cast<ushort4*>(aop + dd) = st;
            }
            {
                const int dd = 32 + 8 * g + hi4;
                ushort4 st = {f2bf(O1[r0] * inv), f2bf(O1[r0 + 1] * inv),
                              f2bf(O1[r0 + 2] * inv), f2bf(O1[r0 + 3] * inv)};
                *reinterpret_cast<ushort4*>(aop + dd) = st;
            }
        }
    }
}

// ---------------------------------------------------------------------------
extern "C" void kernel_launch(void* const* d_in, const int* in_sizes, int n_in,
                              void* d_out, int out_size, void* d_ws, size_t ws_size,
                              hipStream_t stream)
{
    const float* x    = (const float*)d_in[0];
    const float* fcos = (const float*)d_in[1];
    const float* fsin = (const float*)d_in[2];
    const float* wq   = (const float*)d_in[3];
    const float* wk   = (const float*)d_in[4];
    const float* wv   = (const float*)d_in[5];
    const float* wo   = (const float*)d_in[6];
    float* out = (float*)d_out;

    const int M = BATCH * TSEQ;   // 8192

    // workspace: xb | wqkvT | woT | qb | kb(KVH-major) | vt(transposed) | ao
    ushort* xb    = (ushort*)d_ws;
    ushort* wqkvT = xb    + (size_t)M * DIM;
    ushort* woT   = wqkvT + (size_t)NTOT_PAD * DIM;
    ushort* qb    = woT   + (size_t)NO_PAD * DIM;
    ushort* kb    = qb    + (size_t)M * NQ;
    ushort* vt    = kb    + (size_t)M * NKVD;
    ushort* ao    = vt    + (size_t)M * NKVD;

    cvt_x<<<2048, 256, 0, stream>>>(x, xb, M * DIM / 4);
    transpose_wb<<<dim3(30, 30, 4), 256, 0, stream>>>(wq, wk, wv, wo, wqkvT, woT);

    // QKV projection + RoPE (deep-pipelined): 256x256 tiles, grid 7*32 = 224
    gemm_pipe<1, 256><<<dim3((NTOT_PAD / 256) * (M / 256)), 512, 0, stream>>>(
        xb, wqkvT, qb, kb, vt, nullptr, fcos, fsin, NTOT_PAD / 256);

    // causal flash attention (swapped-operand 32x32 MFMA, lane-local softmax)
    attn_mfma<<<dim3(8, NH, BATCH), 256, 0, stream>>>(qb, kb, vt, ao);

    // output projection (deep-pipelined): 256x128 tiles, grid 8*32 = 256
    gemm_pipe<0, 128><<<dim3((NO_PAD / 128) * (M / 256)), 512, 0, stream>>>(
        ao, woT, nullptr, nullptr, nullptr, out, nullptr, nullptr, NO_PAD / 128);
}